// Round 1
// baseline (569.163 us; speedup 1.0000x reference)
//
#include <hip/hip_runtime.h>
#include <hip/hip_bf16.h>
#include <math.h>

#define B_ 4
#define N_ 6
#define FD_ 256
#define D_ 128
#define HF_ 64
#define WF_ 120
#define P_ (HF_*WF_)   // 7680

__device__ inline float wred_sum(float v) {
  #pragma unroll
  for (int o = 32; o > 0; o >>= 1) v += __shfl_xor(v, o, 64);
  return v;
}

// ---------------------------------------------------------------------------
// prep: BN scale/bias folding + homography matrices
// ---------------------------------------------------------------------------
__global__ void prep_kernel(const float* __restrict__ I_src, const float* __restrict__ I_tar_inv,
                            const float* __restrict__ E, const float* __restrict__ dis,
                            const float* __restrict__ norm_vec,
                            const float* __restrict__ bn_gamma, const float* __restrict__ bn_beta,
                            const float* __restrict__ bn_mean, const float* __restrict__ bn_var,
                            float* __restrict__ bnscale, float* __restrict__ bnbias,
                            float* __restrict__ Hm) {
  int t = threadIdx.x;
  if (t < FD_) {
    float s = bn_gamma[t] * rsqrtf(bn_var[t] + 1e-5f);
    bnscale[t] = s;
    bnbias[t] = bn_beta[t] - bn_mean[t] * s;
  }
  if (t < B_*N_) {
    int b = t / N_;
    const float* e = E + t*16;
    const float* nv = norm_vec + b*3;
    float inv_dis = 1.0f / dis[0];
    float M[9];
    #pragma unroll
    for (int r = 0; r < 3; r++)
      #pragma unroll
      for (int c = 0; c < 3; c++)
        M[r*3+c] = e[r*4+c] - e[r*4+3]*nv[c]*inv_dis;
    const float* Is = I_src + t*9;
    float A[9];
    #pragma unroll
    for (int r = 0; r < 3; r++)
      #pragma unroll
      for (int c = 0; c < 3; c++)
        A[r*3+c] = Is[r*3+0]*M[0*3+c] + Is[r*3+1]*M[1*3+c] + Is[r*3+2]*M[2*3+c];
    const float* It = I_tar_inv + b*9;
    #pragma unroll
    for (int r = 0; r < 3; r++)
      #pragma unroll
      for (int c = 0; c < 3; c++)
        Hm[t*9 + r*3+c] = A[r*3+0]*It[0*3+c] + A[r*3+1]*It[1*3+c] + A[r*3+2]*It[2*3+c];
  }
}

// ---------------------------------------------------------------------------
// transpose conv_w (D,FD) -> wT (FD,D) for coalesced GEMM staging
// ---------------------------------------------------------------------------
__global__ void transpose_w_kernel(const float* __restrict__ conv_w, float* __restrict__ wT) {
  int idx = blockIdx.x * 256 + threadIdx.x;   // 0..32767
  int d = idx >> 8, k = idx & 255;
  wT[k*D_ + d] = conv_w[idx];
}

// ---------------------------------------------------------------------------
// conv: val[bn,p,d] = sum_f conv_w[d,f] * relu(bn(feature[bn,f,p]))
// tile: 64 points x 128 d per block, K-chunks of 32 staged in LDS
// ---------------------------------------------------------------------------
__global__ __launch_bounds__(256) void conv_kernel(const float* __restrict__ feature,
    const float* __restrict__ wT, const float* __restrict__ bnscale,
    const float* __restrict__ bnbias, float* __restrict__ val) {
  __shared__ float wt[32*128];
  __shared__ float ft[32*64];
  int tid = threadIdx.x;
  int bn = blockIdx.y;
  int p0 = blockIdx.x * 64;
  const float* fbase = feature + (size_t)bn*FD_*P_ + p0;
  int td = tid & 15, tp = tid >> 4;   // td: 8-d group, tp: 4-p group
  float acc[8][4];
  #pragma unroll
  for (int i = 0; i < 8; i++)
    #pragma unroll
    for (int j = 0; j < 4; j++) acc[i][j] = 0.f;

  for (int k0 = 0; k0 < FD_; k0 += 32) {
    #pragma unroll
    for (int i = 0; i < 2; i++) {
      int idx = tid + i*256;          // float4 units of ft
      int kk = idx >> 4, pc = idx & 15;
      int k = k0 + kk;
      float4 x = *(const float4*)(fbase + (size_t)k*P_ + pc*4);
      float s = bnscale[k], bb = bnbias[k];
      float4 r;
      r.x = fmaxf(x.x*s+bb, 0.f); r.y = fmaxf(x.y*s+bb, 0.f);
      r.z = fmaxf(x.z*s+bb, 0.f); r.w = fmaxf(x.w*s+bb, 0.f);
      *(float4*)&ft[kk*64 + pc*4] = r;
    }
    #pragma unroll
    for (int i = 0; i < 8; i++) {
      int idx = tid + i*256;          // float4 units of wt
      int kk = idx >> 5, dc = idx & 31;
      *(float4*)&wt[kk*128 + dc*4] = *(const float4*)(wT + (size_t)(k0+kk)*128 + dc*4);
    }
    __syncthreads();
    #pragma unroll
    for (int kk = 0; kk < 32; kk++) {
      float4 w0 = *(float4*)&wt[kk*128 + td*8];
      float4 w1 = *(float4*)&wt[kk*128 + td*8 + 4];
      float4 f4 = *(float4*)&ft[kk*64 + tp*4];
      float wr[8] = {w0.x,w0.y,w0.z,w0.w,w1.x,w1.y,w1.z,w1.w};
      float fr[4] = {f4.x,f4.y,f4.z,f4.w};
      #pragma unroll
      for (int i = 0; i < 8; i++)
        #pragma unroll
        for (int j = 0; j < 4; j++)
          acc[i][j] += wr[i]*fr[j];
    }
    __syncthreads();
  }
  #pragma unroll
  for (int j = 0; j < 4; j++) {
    float4 o0 = make_float4(acc[0][j],acc[1][j],acc[2][j],acc[3][j]);
    float4 o1 = make_float4(acc[4][j],acc[5][j],acc[6][j],acc[7][j]);
    float* dst = val + ((size_t)bn*P_ + p0 + tp*4 + j)*D_ + td*8;
    *(float4*)dst = o0;
    *(float4*)(dst+4) = o1;
  }
}

// ---------------------------------------------------------------------------
// att: homography project + bilinear sample + l2norm dot + softmax(n) +
//      weighted sum + residual + LN1.  One wave per point (float2/lane).
// ---------------------------------------------------------------------------
__global__ __launch_bounds__(256) void att_kernel(const float* __restrict__ val,
    const float* __restrict__ Hm, const float* __restrict__ ln1_g,
    const float* __restrict__ ln1_b, float* __restrict__ zbuf) {
  int b = blockIdx.y;
  int p0 = blockIdx.x * 32;
  int wv = threadIdx.x >> 6, ln = threadIdx.x & 63;
  float2 g1  = *(const float2*)(ln1_g + 2*ln);
  float2 be1 = *(const float2*)(ln1_b + 2*ln);

  for (int pi = 0; pi < 8; pi++) {
    int p = p0 + wv*8 + pi;
    int py = p / WF_, px = p - py*WF_;
    float pixx = (float)px * (960.f/119.f);
    float pixy = (float)py * (480.f/63.f);

    const float* qptr = val + ((size_t)(b*N_)*P_ + p)*D_ + 2*ln;
    float2 qv = *(const float2*)qptr;
    float qss = wred_sum(qv.x*qv.x + qv.y*qv.y);
    float qinv = 1.f / fmaxf(sqrtf(qss), 1e-12f);

    float dotv[N_];
    float2 sv[N_];
    #pragma unroll
    for (int n = 0; n < N_; n++) {
      const float* H = Hm + (b*N_+n)*9;
      float hx = H[0]*pixx + H[1]*pixy + H[2];
      float hy = H[3]*pixx + H[4]*pixy + H[5];
      float hz = H[6]*pixx + H[7]*pixy + H[8];
      float sx = (hx/hz) * ((float)WF_/960.f);
      float sy = (hy/hz) * ((float)HF_/480.f);
      float x0f = floorf(sx), y0f = floorf(sy);
      float fx = sx - x0f, fy = sy - y0f;
      int x0 = (int)x0f, y0 = (int)y0f;
      const float* base = val + ((size_t)(b*N_+n)*P_)*D_ + 2*ln;
      float2 acc = make_float2(0.f, 0.f);
      #pragma unroll
      for (int dy = 0; dy < 2; dy++) {
        #pragma unroll
        for (int dx = 0; dx < 2; dx++) {
          int cx = x0 + dx, cy = y0 + dy;
          float wgt = (dx ? fx : 1.f-fx) * (dy ? fy : 1.f-fy);
          bool inb = (cx >= 0) && (cx <= WF_-1) && (cy >= 0) && (cy <= HF_-1);
          int icx = min(max(cx,0),WF_-1), icy = min(max(cy,0),HF_-1);
          float2 g = *(const float2*)(base + (size_t)(icy*WF_+icx)*D_);
          float wm = inb ? wgt : 0.f;
          acc.x += g.x*wm; acc.y += g.y*wm;
        }
      }
      float ss = wred_sum(acc.x*acc.x + acc.y*acc.y);
      float qs = wred_sum(qv.x*acc.x + qv.y*acc.y);
      float dn = qs * qinv / fmaxf(sqrtf(ss), 1e-12f);
      bool valid = (sx >= 0.f) && (sx <= (float)(WF_-1)) && (sy >= 0.f) && (sy <= (float)(HF_-1));
      dotv[n] = valid ? dn : 0.f;
      sv[n] = acc;
    }
    // softmax over n (all lanes hold identical dotv after reductions)
    float m = dotv[0];
    #pragma unroll
    for (int n = 1; n < N_; n++) m = fmaxf(m, dotv[n]);
    float e[N_]; float den = 0.f;
    #pragma unroll
    for (int n = 0; n < N_; n++) { e[n] = expf(dotv[n]-m); den += e[n]; }
    float rden = 1.f/den;
    float2 z = qv;
    #pragma unroll
    for (int n = 0; n < N_; n++) {
      float a = e[n]*rden;
      z.x += a*sv[n].x; z.y += a*sv[n].y;
    }
    // LN1
    float mu = wred_sum(z.x + z.y) * (1.f/128.f);
    float d0 = z.x - mu, d1 = z.y - mu;
    float var = wred_sum(d0*d0 + d1*d1) * (1.f/128.f);
    float rs = rsqrtf(var + 1e-5f);
    float2 o;
    o.x = d0*rs*g1.x + be1.x;
    o.y = d1*rs*g1.y + be1.y;
    *(float2*)(zbuf + ((size_t)b*P_ + p)*D_ + 2*ln) = o;
  }
}

// ---------------------------------------------------------------------------
// mlp: h=gelu(z@W1+b1); y=z+h@W2+b2; LN2; transposed write. 32 points/block.
// ---------------------------------------------------------------------------
__global__ __launch_bounds__(256) void mlp_kernel(const float* __restrict__ zbuf,
    const float* __restrict__ w1, const float* __restrict__ b1,
    const float* __restrict__ w2, const float* __restrict__ b2,
    const float* __restrict__ ln2_g, const float* __restrict__ ln2_b,
    float* __restrict__ out) {
  __shared__ float zt[32*132];
  __shared__ float ht[32*260];
  int tid = threadIdx.x;
  int b = blockIdx.y;
  int p0 = blockIdx.x * 32;

  // stage z tile
  #pragma unroll
  for (int i = 0; i < 4; i++) {
    int idx = tid + i*256;           // float4 units, 1024 total
    int pp = idx >> 5, dc = idx & 31;
    float4 v = *(const float4*)(zbuf + ((size_t)b*P_ + p0 + pp)*D_ + dc*4);
    *(float4*)&zt[pp*132 + dc*4] = v;
  }
  __syncthreads();

  int tj = tid & 31;    // col group
  int tg = tid >> 5;    // point group (4 points each)

  // GEMM1: (32x128)@(128x256), thread computes 4p x 8j
  float acc[4][8];
  #pragma unroll
  for (int i = 0; i < 4; i++)
    #pragma unroll
    for (int j = 0; j < 8; j++) acc[i][j] = 0.f;
  for (int k = 0; k < 128; k += 4) {
    float za[4][4];
    #pragma unroll
    for (int i = 0; i < 4; i++) {
      float4 t = *(float4*)&zt[(tg*4+i)*132 + k];
      za[i][0]=t.x; za[i][1]=t.y; za[i][2]=t.z; za[i][3]=t.w;
    }
    #pragma unroll
    for (int kk = 0; kk < 4; kk++) {
      float4 wa = *(const float4*)(w1 + (size_t)(k+kk)*256 + tj*8);
      float4 wb = *(const float4*)(w1 + (size_t)(k+kk)*256 + tj*8 + 4);
      #pragma unroll
      for (int i = 0; i < 4; i++) {
        float zz = za[i][kk];
        acc[i][0] += zz*wa.x; acc[i][1] += zz*wa.y;
        acc[i][2] += zz*wa.z; acc[i][3] += zz*wa.w;
        acc[i][4] += zz*wb.x; acc[i][5] += zz*wb.y;
        acc[i][6] += zz*wb.z; acc[i][7] += zz*wb.w;
      }
    }
  }
  float4 bb1a = *(const float4*)(b1 + tj*8);
  float4 bb1b = *(const float4*)(b1 + tj*8 + 4);
  float bb1[8] = {bb1a.x,bb1a.y,bb1a.z,bb1a.w,bb1b.x,bb1b.y,bb1b.z,bb1b.w};
  #pragma unroll
  for (int i = 0; i < 4; i++) {
    float hv[8];
    #pragma unroll
    for (int j = 0; j < 8; j++) {
      float x = acc[i][j] + bb1[j];
      hv[j] = 0.5f*x*(1.f + erff(x*0.70710678118654752f));
    }
    *(float4*)&ht[(tg*4+i)*260 + tj*8]     = make_float4(hv[0],hv[1],hv[2],hv[3]);
    *(float4*)&ht[(tg*4+i)*260 + tj*8 + 4] = make_float4(hv[4],hv[5],hv[6],hv[7]);
  }
  __syncthreads();

  // GEMM2: (32x256)@(256x128), thread computes 4p x 4d, + bias + residual
  float acc2[4][4];
  #pragma unroll
  for (int i = 0; i < 4; i++)
    #pragma unroll
    for (int j = 0; j < 4; j++) acc2[i][j] = 0.f;
  for (int k = 0; k < 256; k += 4) {
    float ha[4][4];
    #pragma unroll
    for (int i = 0; i < 4; i++) {
      float4 t = *(float4*)&ht[(tg*4+i)*260 + k];
      ha[i][0]=t.x; ha[i][1]=t.y; ha[i][2]=t.z; ha[i][3]=t.w;
    }
    #pragma unroll
    for (int kk = 0; kk < 4; kk++) {
      float4 w = *(const float4*)(w2 + (size_t)(k+kk)*128 + tj*4);
      #pragma unroll
      for (int i = 0; i < 4; i++) {
        float hh = ha[i][kk];
        acc2[i][0] += hh*w.x; acc2[i][1] += hh*w.y;
        acc2[i][2] += hh*w.z; acc2[i][3] += hh*w.w;
      }
    }
  }
  float4 bb2 = *(const float4*)(b2 + tj*4);
  float y[4][4];
  #pragma unroll
  for (int i = 0; i < 4; i++) {
    y[i][0] = acc2[i][0] + bb2.x + zt[(tg*4+i)*132 + tj*4 + 0];
    y[i][1] = acc2[i][1] + bb2.y + zt[(tg*4+i)*132 + tj*4 + 1];
    y[i][2] = acc2[i][2] + bb2.z + zt[(tg*4+i)*132 + tj*4 + 2];
    y[i][3] = acc2[i][3] + bb2.w + zt[(tg*4+i)*132 + tj*4 + 3];
  }
  __syncthreads();
  float* yt = ht;   // reuse, stride 129 (conflict-free transposed read)
  #pragma unroll
  for (int i = 0; i < 4; i++)
    #pragma unroll
    for (int j = 0; j < 4; j++)
      yt[(tg*4+i)*129 + tj*4 + j] = y[i][j];
  __syncthreads();

  // LN2: wave per 8 points
  int wv = tid >> 6, ln = tid & 63;
  float g0 = ln2_g[2*ln], g1v = ln2_g[2*ln+1];
  float be0 = ln2_b[2*ln], be1v = ln2_b[2*ln+1];
  for (int pi = 0; pi < 8; pi++) {
    int pp = wv*8 + pi;
    float a = yt[pp*129 + 2*ln], c = yt[pp*129 + 2*ln + 1];
    float mu = wred_sum(a + c) * (1.f/128.f);
    float da = a - mu, dc2 = c - mu;
    float var = wred_sum(da*da + dc2*dc2) * (1.f/128.f);
    float rs = rsqrtf(var + 1e-5f);
    yt[pp*129 + 2*ln]     = da*rs*g0 + be0;
    yt[pp*129 + 2*ln + 1] = dc2*rs*g1v + be1v;
  }
  __syncthreads();

  // transposed cooperative write: out[b, d, p]
  #pragma unroll
  for (int i = 0; i < 16; i++) {
    int idx = tid + i*256;    // 0..4095
    int d = idx >> 5, pp = idx & 31;
    out[((size_t)(b*D_ + d))*P_ + p0 + pp] = yt[pp*129 + d];
  }
}

// ---------------------------------------------------------------------------
extern "C" void kernel_launch(void* const* d_in, const int* in_sizes, int n_in,
                              void* d_out, int out_size, void* d_ws, size_t ws_size,
                              hipStream_t stream) {
  (void)in_sizes; (void)n_in; (void)out_size; (void)ws_size;
  const float* feature   = (const float*)d_in[0];
  const float* I_src     = (const float*)d_in[1];
  const float* I_tar_inv = (const float*)d_in[2];
  const float* E         = (const float*)d_in[3];
  const float* dis       = (const float*)d_in[4];
  const float* norm_vec  = (const float*)d_in[5];
  const float* bn_gamma  = (const float*)d_in[6];
  const float* bn_beta   = (const float*)d_in[7];
  const float* bn_mean   = (const float*)d_in[8];
  const float* bn_var    = (const float*)d_in[9];
  const float* conv_w    = (const float*)d_in[10];
  const float* ln1_g     = (const float*)d_in[11];
  const float* ln1_b     = (const float*)d_in[12];
  const float* mlp_w1    = (const float*)d_in[13];
  const float* mlp_b1    = (const float*)d_in[14];
  const float* mlp_w2    = (const float*)d_in[15];
  const float* mlp_b2    = (const float*)d_in[16];
  const float* ln2_g     = (const float*)d_in[17];
  const float* ln2_b     = (const float*)d_in[18];
  float* out = (float*)d_out;

  char* ws = (char*)d_ws;
  float* bnscale = (float*)(ws + 0);
  float* bnbias  = (float*)(ws + 1024);
  float* Hm      = (float*)(ws + 2048);
  float* wT      = (float*)(ws + 4096);
  float* val     = (float*)(ws + 4096 + 131072);                 // (B,N,P,D) fp32, 94.4 MB
  float* zbuf    = (float*)(ws + 4096 + 131072 + 94371840ULL);   // (B,P,D) fp32, 15.7 MB

  hipLaunchKernelGGL(prep_kernel, dim3(1), dim3(256), 0, stream,
                     I_src, I_tar_inv, E, dis, norm_vec,
                     bn_gamma, bn_beta, bn_mean, bn_var, bnscale, bnbias, Hm);
  hipLaunchKernelGGL(transpose_w_kernel, dim3(128), dim3(256), 0, stream, conv_w, wT);
  hipLaunchKernelGGL(conv_kernel, dim3(120, 24), dim3(256), 0, stream,
                     feature, wT, bnscale, bnbias, val);
  hipLaunchKernelGGL(att_kernel, dim3(240, 4), dim3(256), 0, stream,
                     val, Hm, ln1_g, ln1_b, zbuf);
  hipLaunchKernelGGL(mlp_kernel, dim3(240, 4), dim3(256), 0, stream,
                     zbuf, mlp_w1, mlp_b1, mlp_w2, mlp_b2, ln2_g, ln2_b, out);
}

// Round 2
// 473.914 us; speedup vs baseline: 1.2010x; 1.2010x over previous
//
#include <hip/hip_runtime.h>
#include <hip/hip_bf16.h>
#include <math.h>

#define B_ 4
#define N_ 6
#define FD_ 256
#define D_ 128
#define HF_ 64
#define WF_ 120
#define P_ (HF_*WF_)   // 7680

typedef __attribute__((ext_vector_type(8))) short short8;
typedef __attribute__((ext_vector_type(4))) float floatx4;

__device__ inline float wred_sum(float v) {
  #pragma unroll
  for (int o = 32; o > 0; o >>= 1) v += __shfl_xor(v, o, 64);
  return v;
}

__device__ inline unsigned short f2bf(float f) {
  unsigned int u = __builtin_bit_cast(unsigned int, f);
  u += 0x7fffu + ((u >> 16) & 1u);   // RNE
  return (unsigned short)(u >> 16);
}

// ---------------------------------------------------------------------------
// prep: BN scale/bias folding + homography matrices
// ---------------------------------------------------------------------------
__global__ void prep_kernel(const float* __restrict__ I_src, const float* __restrict__ I_tar_inv,
                            const float* __restrict__ E, const float* __restrict__ dis,
                            const float* __restrict__ norm_vec,
                            const float* __restrict__ bn_gamma, const float* __restrict__ bn_beta,
                            const float* __restrict__ bn_mean, const float* __restrict__ bn_var,
                            float* __restrict__ bnscale, float* __restrict__ bnbias,
                            float* __restrict__ Hm) {
  int t = threadIdx.x;
  if (t < FD_) {
    float s = bn_gamma[t] * rsqrtf(bn_var[t] + 1e-5f);
    bnscale[t] = s;
    bnbias[t] = bn_beta[t] - bn_mean[t] * s;
  }
  if (t < B_*N_) {
    int b = t / N_;
    const float* e = E + t*16;
    const float* nv = norm_vec + b*3;
    float inv_dis = 1.0f / dis[0];
    float M[9];
    #pragma unroll
    for (int r = 0; r < 3; r++)
      #pragma unroll
      for (int c = 0; c < 3; c++)
        M[r*3+c] = e[r*4+c] - e[r*4+3]*nv[c]*inv_dis;
    const float* Is = I_src + t*9;
    float A[9];
    #pragma unroll
    for (int r = 0; r < 3; r++)
      #pragma unroll
      for (int c = 0; c < 3; c++)
        A[r*3+c] = Is[r*3+0]*M[0*3+c] + Is[r*3+1]*M[1*3+c] + Is[r*3+2]*M[2*3+c];
    const float* It = I_tar_inv + b*9;
    #pragma unroll
    for (int r = 0; r < 3; r++)
      #pragma unroll
      for (int c = 0; c < 3; c++)
        Hm[t*9 + r*3+c] = A[r*3+0]*It[0*3+c] + A[r*3+1]*It[1*3+c] + A[r*3+2]*It[2*3+c];
  }
}

// ---------------------------------------------------------------------------
// swizzle conv_w (D,FD) fp32 -> bf16 B-fragment order:
// wswz[((kc*8 + dt)*64 + lane)*8 + j] = bf16(W[k][d]),
//   d = dt*16 + (lane&15), k = kc*32 + (lane>>4)*8 + j, W[k][d] = conv_w[d*FD + k]
// ---------------------------------------------------------------------------
__global__ void swizzle_w_kernel(const float* __restrict__ conv_w, unsigned short* __restrict__ wswz) {
  int t = blockIdx.x * 256 + threadIdx.x;   // 0..32767
  int j    =  t        & 7;
  int lane = (t >> 3)  & 63;
  int dt   = (t >> 9)  & 7;
  int kc   =  t >> 12;
  int d = dt*16 + (lane & 15);
  int k = kc*32 + (lane >> 4)*8 + j;
  wswz[t] = f2bf(conv_w[d*FD_ + k]);
}

// ---------------------------------------------------------------------------
// conv (MFMA): val[bn,p,d] = sum_k relu(bn(feature[bn,k,p])) * W[k,d]
// block: 64 p x 128 d, 4 waves (16 p each x 128 d), K chunks of 32.
// ---------------------------------------------------------------------------
#define KP_ 40   // padded LDS row stride (bf16 elems) for A tile
__global__ __launch_bounds__(256) void conv_kernel(const float* __restrict__ feature,
    const unsigned short* __restrict__ wswz, const float* __restrict__ bnscale,
    const float* __restrict__ bnbias, float* __restrict__ val) {
  __shared__ unsigned short apad[64*KP_];   // 5120 B
  __shared__ unsigned short wlds[4096];     // 8192 B
  __shared__ float sbn[512];

  int tid = threadIdx.x;
  int bn = blockIdx.y;
  int p0 = blockIdx.x * 64;

  if (tid < 256) { sbn[tid] = bnscale[tid]; sbn[256+tid] = bnbias[tid]; }

  int ap = tid & 63;     // staging point
  int kg = tid >> 6;     // staging k-group (wave-uniform)
  const float* fbase = feature + (size_t)bn*FD_*P_ + p0 + ap;

  int ln = tid & 63;
  int wv = tid >> 6;
  int m = ln & 15;       // A row within 16, also C/D col index (d)
  int q = ln >> 4;       // quad

  floatx4 acc[8];
  #pragma unroll
  for (int dt = 0; dt < 8; dt++) acc[dt] = (floatx4){0.f,0.f,0.f,0.f};

  const unsigned short* aaddr = &apad[(wv*16 + m)*KP_ + q*8];

  for (int kc = 0; kc < 8; kc++) {
    int k0 = kc*32;
    // ---- load A column (8 k values for this p), BN+ReLU, pack bf16 ----
    float xv[8];
    #pragma unroll
    for (int j = 0; j < 8; j++)
      xv[j] = fbase[(size_t)(k0 + kg*8 + j)*P_];
    // ---- load W chunk (straight copy, 32 B/thread) ----
    uint4 w0 = *(const uint4*)(wswz + (size_t)kc*4096 + tid*16);
    uint4 w1 = *(const uint4*)(wswz + (size_t)kc*4096 + tid*16 + 8);
    unsigned int pk[4];
    #pragma unroll
    for (int jj = 0; jj < 4; jj++) {
      float a0 = xv[2*jj],   a1 = xv[2*jj+1];
      float s0 = sbn[k0+kg*8+2*jj],   b0 = sbn[256+k0+kg*8+2*jj];
      float s1 = sbn[k0+kg*8+2*jj+1], b1 = sbn[256+k0+kg*8+2*jj+1];
      unsigned short h0 = f2bf(fmaxf(a0*s0+b0, 0.f));
      unsigned short h1 = f2bf(fmaxf(a1*s1+b1, 0.f));
      pk[jj] = (unsigned int)h0 | ((unsigned int)h1 << 16);
    }
    __syncthreads();   // prior chunk's LDS reads complete
    *(uint4*)&apad[ap*KP_ + kg*8] = make_uint4(pk[0],pk[1],pk[2],pk[3]);
    *(uint4*)&wlds[tid*16]     = w0;
    *(uint4*)&wlds[tid*16 + 8] = w1;
    __syncthreads();
    // ---- MFMA ----
    short8 af = *(const short8*)aaddr;
    #pragma unroll
    for (int dt = 0; dt < 8; dt++) {
      short8 bfg = *(const short8*)&wlds[(dt*64 + ln)*8];
      acc[dt] = __builtin_amdgcn_mfma_f32_16x16x32_bf16(af, bfg, acc[dt], 0, 0, 0);
    }
  }
  // ---- epilogue: C/D col = lane&15 (d), row = quad*4+reg (p) ----
  #pragma unroll
  for (int dt = 0; dt < 8; dt++) {
    #pragma unroll
    for (int r = 0; r < 4; r++) {
      int pp = p0 + wv*16 + q*4 + r;
      int d  = dt*16 + m;
      val[((size_t)bn*P_ + pp)*D_ + d] = acc[dt][r];
    }
  }
}

// ---------------------------------------------------------------------------
// att: homography project + bilinear sample + l2norm dot + softmax(n) +
//      weighted sum + residual + LN1.  One wave per point (float2/lane).
// ---------------------------------------------------------------------------
__global__ __launch_bounds__(256) void att_kernel(const float* __restrict__ val,
    const float* __restrict__ Hm, const float* __restrict__ ln1_g,
    const float* __restrict__ ln1_b, float* __restrict__ zbuf) {
  int b = blockIdx.y;
  int p0 = blockIdx.x * 32;
  int wv = threadIdx.x >> 6, ln = threadIdx.x & 63;
  float2 g1  = *(const float2*)(ln1_g + 2*ln);
  float2 be1 = *(const float2*)(ln1_b + 2*ln);

  for (int pi = 0; pi < 8; pi++) {
    int p = p0 + wv*8 + pi;
    int py = p / WF_, px = p - py*WF_;
    float pixx = (float)px * (960.f/119.f);
    float pixy = (float)py * (480.f/63.f);

    const float* qptr = val + ((size_t)(b*N_)*P_ + p)*D_ + 2*ln;
    float2 qv = *(const float2*)qptr;
    float qss = wred_sum(qv.x*qv.x + qv.y*qv.y);
    float qinv = 1.f / fmaxf(sqrtf(qss), 1e-12f);

    float dotv[N_];
    float2 sv[N_];
    #pragma unroll
    for (int n = 0; n < N_; n++) {
      const float* H = Hm + (b*N_+n)*9;
      float hx = H[0]*pixx + H[1]*pixy + H[2];
      float hy = H[3]*pixx + H[4]*pixy + H[5];
      float hz = H[6]*pixx + H[7]*pixy + H[8];
      float sx = (hx/hz) * ((float)WF_/960.f);
      float sy = (hy/hz) * ((float)HF_/480.f);
      float x0f = floorf(sx), y0f = floorf(sy);
      float fx = sx - x0f, fy = sy - y0f;
      int x0 = (int)x0f, y0 = (int)y0f;
      const float* base = val + ((size_t)(b*N_+n)*P_)*D_ + 2*ln;
      float2 acc = make_float2(0.f, 0.f);
      #pragma unroll
      for (int dy = 0; dy < 2; dy++) {
        #pragma unroll
        for (int dx = 0; dx < 2; dx++) {
          int cx = x0 + dx, cy = y0 + dy;
          float wgt = (dx ? fx : 1.f-fx) * (dy ? fy : 1.f-fy);
          bool inb = (cx >= 0) && (cx <= WF_-1) && (cy >= 0) && (cy <= HF_-1);
          int icx = min(max(cx,0),WF_-1), icy = min(max(cy,0),HF_-1);
          float2 g = *(const float2*)(base + (size_t)(icy*WF_+icx)*D_);
          float wm = inb ? wgt : 0.f;
          acc.x += g.x*wm; acc.y += g.y*wm;
        }
      }
      float ss = wred_sum(acc.x*acc.x + acc.y*acc.y);
      float qs = wred_sum(qv.x*acc.x + qv.y*acc.y);
      float dn = qs * qinv / fmaxf(sqrtf(ss), 1e-12f);
      bool valid = (sx >= 0.f) && (sx <= (float)(WF_-1)) && (sy >= 0.f) && (sy <= (float)(HF_-1));
      dotv[n] = valid ? dn : 0.f;
      sv[n] = acc;
    }
    // softmax over n (all lanes hold identical dotv after reductions)
    float m = dotv[0];
    #pragma unroll
    for (int n = 1; n < N_; n++) m = fmaxf(m, dotv[n]);
    float e[N_]; float den = 0.f;
    #pragma unroll
    for (int n = 0; n < N_; n++) { e[n] = expf(dotv[n]-m); den += e[n]; }
    float rden = 1.f/den;
    float2 z = qv;
    #pragma unroll
    for (int n = 0; n < N_; n++) {
      float a = e[n]*rden;
      z.x += a*sv[n].x; z.y += a*sv[n].y;
    }
    // LN1
    float mu = wred_sum(z.x + z.y) * (1.f/128.f);
    float d0 = z.x - mu, d1 = z.y - mu;
    float var = wred_sum(d0*d0 + d1*d1) * (1.f/128.f);
    float rs = rsqrtf(var + 1e-5f);
    float2 o;
    o.x = d0*rs*g1.x + be1.x;
    o.y = d1*rs*g1.y + be1.y;
    *(float2*)(zbuf + ((size_t)b*P_ + p)*D_ + 2*ln) = o;
  }
}

// ---------------------------------------------------------------------------
// mlp: h=gelu(z@W1+b1); y=z+h@W2+b2; LN2; transposed write. 32 points/block.
// ---------------------------------------------------------------------------
__global__ __launch_bounds__(256) void mlp_kernel(const float* __restrict__ zbuf,
    const float* __restrict__ w1, const float* __restrict__ b1,
    const float* __restrict__ w2, const float* __restrict__ b2,
    const float* __restrict__ ln2_g, const float* __restrict__ ln2_b,
    float* __restrict__ out) {
  __shared__ float zt[32*132];
  __shared__ float ht[32*260];
  int tid = threadIdx.x;
  int b = blockIdx.y;
  int p0 = blockIdx.x * 32;

  // stage z tile
  #pragma unroll
  for (int i = 0; i < 4; i++) {
    int idx = tid + i*256;           // float4 units, 1024 total
    int pp = idx >> 5, dc = idx & 31;
    float4 v = *(const float4*)(zbuf + ((size_t)b*P_ + p0 + pp)*D_ + dc*4);
    *(float4*)&zt[pp*132 + dc*4] = v;
  }
  __syncthreads();

  int tj = tid & 31;    // col group
  int tg = tid >> 5;    // point group (4 points each)

  // GEMM1: (32x128)@(128x256), thread computes 4p x 8j
  float acc[4][8];
  #pragma unroll
  for (int i = 0; i < 4; i++)
    #pragma unroll
    for (int j = 0; j < 8; j++) acc[i][j] = 0.f;
  for (int k = 0; k < 128; k += 4) {
    float za[4][4];
    #pragma unroll
    for (int i = 0; i < 4; i++) {
      float4 t = *(float4*)&zt[(tg*4+i)*132 + k];
      za[i][0]=t.x; za[i][1]=t.y; za[i][2]=t.z; za[i][3]=t.w;
    }
    #pragma unroll
    for (int kk = 0; kk < 4; kk++) {
      float4 wa = *(const float4*)(w1 + (size_t)(k+kk)*256 + tj*8);
      float4 wb = *(const float4*)(w1 + (size_t)(k+kk)*256 + tj*8 + 4);
      #pragma unroll
      for (int i = 0; i < 4; i++) {
        float zz = za[i][kk];
        acc[i][0] += zz*wa.x; acc[i][1] += zz*wa.y;
        acc[i][2] += zz*wa.z; acc[i][3] += zz*wa.w;
        acc[i][4] += zz*wb.x; acc[i][5] += zz*wb.y;
        acc[i][6] += zz*wb.z; acc[i][7] += zz*wb.w;
      }
    }
  }
  float4 bb1a = *(const float4*)(b1 + tj*8);
  float4 bb1b = *(const float4*)(b1 + tj*8 + 4);
  float bb1[8] = {bb1a.x,bb1a.y,bb1a.z,bb1a.w,bb1b.x,bb1b.y,bb1b.z,bb1b.w};
  #pragma unroll
  for (int i = 0; i < 4; i++) {
    float hv[8];
    #pragma unroll
    for (int j = 0; j < 8; j++) {
      float x = acc[i][j] + bb1[j];
      hv[j] = 0.5f*x*(1.f + erff(x*0.70710678118654752f));
    }
    *(float4*)&ht[(tg*4+i)*260 + tj*8]     = make_float4(hv[0],hv[1],hv[2],hv[3]);
    *(float4*)&ht[(tg*4+i)*260 + tj*8 + 4] = make_float4(hv[4],hv[5],hv[6],hv[7]);
  }
  __syncthreads();

  // GEMM2: (32x256)@(256x128), thread computes 4p x 4d, + bias + residual
  float acc2[4][4];
  #pragma unroll
  for (int i = 0; i < 4; i++)
    #pragma unroll
    for (int j = 0; j < 4; j++) acc2[i][j] = 0.f;
  for (int k = 0; k < 256; k += 4) {
    float ha[4][4];
    #pragma unroll
    for (int i = 0; i < 4; i++) {
      float4 t = *(float4*)&ht[(tg*4+i)*260 + k];
      ha[i][0]=t.x; ha[i][1]=t.y; ha[i][2]=t.z; ha[i][3]=t.w;
    }
    #pragma unroll
    for (int kk = 0; kk < 4; kk++) {
      float4 w = *(const float4*)(w2 + (size_t)(k+kk)*128 + tj*4);
      #pragma unroll
      for (int i = 0; i < 4; i++) {
        float hh = ha[i][kk];
        acc2[i][0] += hh*w.x; acc2[i][1] += hh*w.y;
        acc2[i][2] += hh*w.z; acc2[i][3] += hh*w.w;
      }
    }
  }
  float4 bb2 = *(const float4*)(b2 + tj*4);
  float y[4][4];
  #pragma unroll
  for (int i = 0; i < 4; i++) {
    y[i][0] = acc2[i][0] + bb2.x + zt[(tg*4+i)*132 + tj*4 + 0];
    y[i][1] = acc2[i][1] + bb2.y + zt[(tg*4+i)*132 + tj*4 + 1];
    y[i][2] = acc2[i][2] + bb2.z + zt[(tg*4+i)*132 + tj*4 + 2];
    y[i][3] = acc2[i][3] + bb2.w + zt[(tg*4+i)*132 + tj*4 + 3];
  }
  __syncthreads();
  float* yt = ht;   // reuse, stride 129 (conflict-free transposed read)
  #pragma unroll
  for (int i = 0; i < 4; i++)
    #pragma unroll
    for (int j = 0; j < 4; j++)
      yt[(tg*4+i)*129 + tj*4 + j] = y[i][j];
  __syncthreads();

  // LN2: wave per 8 points
  int wv = tid >> 6, ln = tid & 63;
  float g0 = ln2_g[2*ln], g1v = ln2_g[2*ln+1];
  float be0 = ln2_b[2*ln], be1v = ln2_b[2*ln+1];
  for (int pi = 0; pi < 8; pi++) {
    int pp = wv*8 + pi;
    float a = yt[pp*129 + 2*ln], c = yt[pp*129 + 2*ln + 1];
    float mu = wred_sum(a + c) * (1.f/128.f);
    float da = a - mu, dc2 = c - mu;
    float var = wred_sum(da*da + dc2*dc2) * (1.f/128.f);
    float rs = rsqrtf(var + 1e-5f);
    yt[pp*129 + 2*ln]     = da*rs*g0 + be0;
    yt[pp*129 + 2*ln + 1] = dc2*rs*g1v + be1v;
  }
  __syncthreads();

  // transposed cooperative write: out[b, d, p]
  #pragma unroll
  for (int i = 0; i < 16; i++) {
    int idx = tid + i*256;    // 0..4095
    int d = idx >> 5, pp = idx & 31;
    out[((size_t)(b*D_ + d))*P_ + p0 + pp] = yt[pp*129 + d];
  }
}

// ---------------------------------------------------------------------------
extern "C" void kernel_launch(void* const* d_in, const int* in_sizes, int n_in,
                              void* d_out, int out_size, void* d_ws, size_t ws_size,
                              hipStream_t stream) {
  (void)in_sizes; (void)n_in; (void)out_size; (void)ws_size;
  const float* feature   = (const float*)d_in[0];
  const float* I_src     = (const float*)d_in[1];
  const float* I_tar_inv = (const float*)d_in[2];
  const float* E         = (const float*)d_in[3];
  const float* dis       = (const float*)d_in[4];
  const float* norm_vec  = (const float*)d_in[5];
  const float* bn_gamma  = (const float*)d_in[6];
  const float* bn_beta   = (const float*)d_in[7];
  const float* bn_mean   = (const float*)d_in[8];
  const float* bn_var    = (const float*)d_in[9];
  const float* conv_w    = (const float*)d_in[10];
  const float* ln1_g     = (const float*)d_in[11];
  const float* ln1_b     = (const float*)d_in[12];
  const float* mlp_w1    = (const float*)d_in[13];
  const float* mlp_b1    = (const float*)d_in[14];
  const float* mlp_w2    = (const float*)d_in[15];
  const float* mlp_b2    = (const float*)d_in[16];
  const float* ln2_g     = (const float*)d_in[17];
  const float* ln2_b     = (const float*)d_in[18];
  float* out = (float*)d_out;

  char* ws = (char*)d_ws;
  float* bnscale          = (float*)(ws + 0);
  float* bnbias           = (float*)(ws + 1024);
  float* Hm               = (float*)(ws + 2048);
  unsigned short* wswz    = (unsigned short*)(ws + 4096);        // 64 KB
  float* val  = (float*)(ws + 4096 + 131072);                    // (B,N,P,D) fp32, 94.4 MB
  float* zbuf = (float*)(ws + 4096 + 131072 + 94371840ULL);      // (B,P,D) fp32, 15.7 MB

  hipLaunchKernelGGL(prep_kernel, dim3(1), dim3(256), 0, stream,
                     I_src, I_tar_inv, E, dis, norm_vec,
                     bn_gamma, bn_beta, bn_mean, bn_var, bnscale, bnbias, Hm);
  hipLaunchKernelGGL(swizzle_w_kernel, dim3(128), dim3(256), 0, stream, conv_w, wswz);
  hipLaunchKernelGGL(conv_kernel, dim3(120, 24), dim3(256), 0, stream,
                     feature, wswz, bnscale, bnbias, val);
  hipLaunchKernelGGL(att_kernel, dim3(240, 4), dim3(256), 0, stream,
                     val, Hm, ln1_g, ln1_b, zbuf);
  hipLaunchKernelGGL(mlp_kernel, dim3(240, 4), dim3(256), 0, stream,
                     zbuf, mlp_w1, mlp_b1, mlp_w2, mlp_b2, ln2_g, ln2_b, out);
}

// Round 3
// 429.671 us; speedup vs baseline: 1.3247x; 1.1030x over previous
//
#include <hip/hip_runtime.h>
#include <hip/hip_bf16.h>
#include <math.h>

#define B_ 4
#define N_ 6
#define FD_ 256
#define D_ 128
#define HF_ 64
#define WF_ 120
#define P_ (HF_*WF_)   // 7680

typedef __attribute__((ext_vector_type(8))) short short8;
typedef __attribute__((ext_vector_type(4))) float floatx4;
typedef __attribute__((ext_vector_type(4))) unsigned int uint4e;

__device__ inline float gred_sum(float v) {   // sum within 16-lane group
  v += __shfl_xor(v, 1); v += __shfl_xor(v, 2);
  v += __shfl_xor(v, 4); v += __shfl_xor(v, 8);
  return v;
}

__device__ inline unsigned short f2bf(float f) {
  unsigned int u = __builtin_bit_cast(unsigned int, f);
  u += 0x7fffu + ((u >> 16) & 1u);   // RNE
  return (unsigned short)(u >> 16);
}
__device__ inline float bf2f(unsigned short h) {
  return __builtin_bit_cast(float, ((unsigned int)h) << 16);
}

// ---------------------------------------------------------------------------
// prep: BN scale/bias folding + homography matrices
// ---------------------------------------------------------------------------
__global__ void prep_kernel(const float* __restrict__ I_src, const float* __restrict__ I_tar_inv,
                            const float* __restrict__ E, const float* __restrict__ dis,
                            const float* __restrict__ norm_vec,
                            const float* __restrict__ bn_gamma, const float* __restrict__ bn_beta,
                            const float* __restrict__ bn_mean, const float* __restrict__ bn_var,
                            float* __restrict__ bnscale, float* __restrict__ bnbias,
                            float* __restrict__ Hm) {
  int t = threadIdx.x;
  if (t < FD_) {
    float s = bn_gamma[t] * rsqrtf(bn_var[t] + 1e-5f);
    bnscale[t] = s;
    bnbias[t] = bn_beta[t] - bn_mean[t] * s;
  }
  if (t < B_*N_) {
    int b = t / N_;
    const float* e = E + t*16;
    const float* nv = norm_vec + b*3;
    float inv_dis = 1.0f / dis[0];
    float M[9];
    #pragma unroll
    for (int r = 0; r < 3; r++)
      #pragma unroll
      for (int c = 0; c < 3; c++)
        M[r*3+c] = e[r*4+c] - e[r*4+3]*nv[c]*inv_dis;
    const float* Is = I_src + t*9;
    float A[9];
    #pragma unroll
    for (int r = 0; r < 3; r++)
      #pragma unroll
      for (int c = 0; c < 3; c++)
        A[r*3+c] = Is[r*3+0]*M[0*3+c] + Is[r*3+1]*M[1*3+c] + Is[r*3+2]*M[2*3+c];
    const float* It = I_tar_inv + b*9;
    #pragma unroll
    for (int r = 0; r < 3; r++)
      #pragma unroll
      for (int c = 0; c < 3; c++)
        Hm[t*9 + r*3+c] = A[r*3+0]*It[0*3+c] + A[r*3+1]*It[1*3+c] + A[r*3+2]*It[2*3+c];
  }
}

// ---------------------------------------------------------------------------
// swizzle conv_w (D,FD) fp32 -> bf16 B-fragment order (t = ((kc*8+dt)*64+ln)*8+j)
// ---------------------------------------------------------------------------
__global__ void swizzle_w_kernel(const float* __restrict__ conv_w, unsigned short* __restrict__ wswz) {
  int t = blockIdx.x * 256 + threadIdx.x;   // 0..32767
  int j    =  t        & 7;
  int lane = (t >> 3)  & 63;
  int dt   = (t >> 9)  & 7;
  int kc   =  t >> 12;
  int d = dt*16 + (lane & 15);
  int k = kc*32 + (lane >> 4)*8 + j;
  wswz[t] = f2bf(conv_w[d*FD_ + k]);
}

// ---------------------------------------------------------------------------
// swizzle mlp weights to B-frag order bf16:
//  w1s: [kc<4][dt<16][ln][j]  from w1(128x256);  w2s: [kc<8][dt<8][ln][j] from w2(256x128)
// ---------------------------------------------------------------------------
__global__ void swizzle_mlp_kernel(const float* __restrict__ w1, const float* __restrict__ w2,
                                   unsigned short* __restrict__ w1s, unsigned short* __restrict__ w2s) {
  int t = blockIdx.x * 256 + threadIdx.x;   // 0..65535
  if (t < 32768) {
    int j    =  t        & 7;
    int lane = (t >> 3)  & 63;
    int dt   = (t >> 9)  & 15;
    int kc   =  t >> 13;
    int n = dt*16 + (lane & 15);
    int k = kc*32 + (lane >> 4)*8 + j;
    w1s[t] = f2bf(w1[k*256 + n]);
  } else {
    int u = t - 32768;
    int j    =  u        & 7;
    int lane = (u >> 3)  & 63;
    int dt   = (u >> 9)  & 7;
    int kc   =  u >> 12;
    int n = dt*16 + (lane & 15);
    int k = kc*32 + (lane >> 4)*8 + j;
    w2s[u] = f2bf(w2[k*128 + n]);
  }
}

// ---------------------------------------------------------------------------
// conv (MFMA, no LDS tiles, no barriers): A-frags built in registers from
// feature (BN+ReLU+bf16 pack), B-frags streamed from wswz (L2-resident).
// block: 64 p x 128 d, 4 waves (16 p each).
// ---------------------------------------------------------------------------
__global__ __launch_bounds__(256) void conv_kernel(const float* __restrict__ feature,
    const unsigned short* __restrict__ wswz, const float* __restrict__ bnscale,
    const float* __restrict__ bnbias, float* __restrict__ val) {
  __shared__ float sbn[512];
  int tid = threadIdx.x;
  if (tid < 256) { sbn[tid] = bnscale[tid]; sbn[256+tid] = bnbias[tid]; }
  __syncthreads();

  int bn = blockIdx.y;
  int p0 = blockIdx.x * 64;
  int ln = tid & 63, wv = tid >> 6;
  int m = ln & 15, q = ln >> 4;
  const float* fbase = feature + (size_t)bn*FD_*P_ + p0 + wv*16 + m;

  floatx4 acc[8];
  #pragma unroll
  for (int dt = 0; dt < 8; dt++) acc[dt] = (floatx4){0.f,0.f,0.f,0.f};

  for (int kc = 0; kc < 8; kc++) {
    int kb = kc*32 + q*8;
    float xv[8];
    #pragma unroll
    for (int j = 0; j < 8; j++)
      xv[j] = fbase[(size_t)(kb + j)*P_];
    unsigned int pk[4];
    #pragma unroll
    for (int jj = 0; jj < 4; jj++) {
      float s0 = sbn[kb+2*jj],   b0 = sbn[256+kb+2*jj];
      float s1 = sbn[kb+2*jj+1], b1 = sbn[256+kb+2*jj+1];
      unsigned short h0 = f2bf(fmaxf(xv[2*jj]*s0+b0, 0.f));
      unsigned short h1 = f2bf(fmaxf(xv[2*jj+1]*s1+b1, 0.f));
      pk[jj] = (unsigned int)h0 | ((unsigned int)h1 << 16);
    }
    uint4e ua = {pk[0], pk[1], pk[2], pk[3]};
    short8 af = __builtin_bit_cast(short8, ua);
    #pragma unroll
    for (int dt = 0; dt < 8; dt++) {
      short8 bfg = *(const short8*)(wswz + (((size_t)kc*8 + dt)*64 + ln)*8);
      acc[dt] = __builtin_amdgcn_mfma_f32_16x16x32_bf16(af, bfg, acc[dt], 0, 0, 0);
    }
  }
  // epilogue: C/D col = lane&15 (d), row = quad*4+reg (p)
  #pragma unroll
  for (int dt = 0; dt < 8; dt++) {
    #pragma unroll
    for (int r = 0; r < 4; r++) {
      int pp = p0 + wv*16 + q*4 + r;
      int d  = dt*16 + m;
      val[((size_t)bn*P_ + pp)*D_ + d] = acc[dt][r];
    }
  }
}

// ---------------------------------------------------------------------------
// att: 16-lane group per point (8 floats/lane), 4 points per wave.
// homography + bilinear sample + normalized dot + softmax(n) + residual + LN1
// ---------------------------------------------------------------------------
__global__ __launch_bounds__(256) void att_kernel(const float* __restrict__ val,
    const float* __restrict__ Hm, const float* __restrict__ ln1_g,
    const float* __restrict__ ln1_b, float* __restrict__ zbuf) {
  int b = blockIdx.y;
  int p0 = blockIdx.x * 32;
  int tid = threadIdx.x;
  int ln = tid & 63, wv = tid >> 6;
  int grp = ln >> 4, c = ln & 15;   // lane's d-range: c*8 .. c*8+7

  float g1[8], be1[8];
  *(float4*)&g1[0]  = *(const float4*)(ln1_g + c*8);
  *(float4*)&g1[4]  = *(const float4*)(ln1_g + c*8 + 4);
  *(float4*)&be1[0] = *(const float4*)(ln1_b + c*8);
  *(float4*)&be1[4] = *(const float4*)(ln1_b + c*8 + 4);

  for (int pi = 0; pi < 2; pi++) {
    int p = p0 + wv*8 + grp*2 + pi;
    int py = p / WF_, px = p - py*WF_;
    float pixx = (float)px * (960.f/119.f);
    float pixy = (float)py * (480.f/63.f);

    const float* qptr = val + ((size_t)(b*N_)*P_ + p)*D_ + c*8;
    float qv[8];
    *(float4*)&qv[0] = *(const float4*)qptr;
    *(float4*)&qv[4] = *(const float4*)(qptr + 4);
    float qp = 0.f;
    #pragma unroll
    for (int i = 0; i < 8; i++) qp += qv[i]*qv[i];
    float qinv = 1.f / fmaxf(sqrtf(gred_sum(qp)), 1e-12f);

    float dotv[N_];
    float sv[N_][8];
    #pragma unroll
    for (int n = 0; n < N_; n++) {
      const float* H = Hm + (b*N_+n)*9;
      float hx = H[0]*pixx + H[1]*pixy + H[2];
      float hy = H[3]*pixx + H[4]*pixy + H[5];
      float hz = H[6]*pixx + H[7]*pixy + H[8];
      float sx = (hx/hz) * ((float)WF_/960.f);
      float sy = (hy/hz) * ((float)HF_/480.f);
      float x0f = floorf(sx), y0f = floorf(sy);
      float fx = sx - x0f, fy = sy - y0f;
      int x0 = (int)x0f, y0 = (int)y0f;
      const float* base = val + ((size_t)(b*N_+n)*P_)*D_ + c*8;
      float acc[8];
      #pragma unroll
      for (int i = 0; i < 8; i++) acc[i] = 0.f;
      #pragma unroll
      for (int dy = 0; dy < 2; dy++) {
        #pragma unroll
        for (int dx = 0; dx < 2; dx++) {
          int cx = x0 + dx, cy = y0 + dy;
          float wgt = (dx ? fx : 1.f-fx) * (dy ? fy : 1.f-fy);
          bool inb = (cx >= 0) && (cx <= WF_-1) && (cy >= 0) && (cy <= HF_-1);
          int icx = min(max(cx,0),WF_-1), icy = min(max(cy,0),HF_-1);
          const float* gp = base + (size_t)(icy*WF_ + icx)*D_;
          float4 ga = *(const float4*)gp;
          float4 gb = *(const float4*)(gp + 4);
          float wm = inb ? wgt : 0.f;
          acc[0] += ga.x*wm; acc[1] += ga.y*wm; acc[2] += ga.z*wm; acc[3] += ga.w*wm;
          acc[4] += gb.x*wm; acc[5] += gb.y*wm; acc[6] += gb.z*wm; acc[7] += gb.w*wm;
        }
      }
      float ssp = 0.f, qsp = 0.f;
      #pragma unroll
      for (int i = 0; i < 8; i++) { ssp += acc[i]*acc[i]; qsp += qv[i]*acc[i]; }
      float ss = gred_sum(ssp);
      float qs = gred_sum(qsp);
      float dn = qs * qinv / fmaxf(sqrtf(ss), 1e-12f);
      bool valid = (sx >= 0.f) && (sx <= (float)(WF_-1)) && (sy >= 0.f) && (sy <= (float)(HF_-1));
      dotv[n] = valid ? dn : 0.f;
      #pragma unroll
      for (int i = 0; i < 8; i++) sv[n][i] = acc[i];
    }
    // softmax over n (uniform within 16-lane group)
    float mx = dotv[0];
    #pragma unroll
    for (int n = 1; n < N_; n++) mx = fmaxf(mx, dotv[n]);
    float e[N_]; float den = 0.f;
    #pragma unroll
    for (int n = 0; n < N_; n++) { e[n] = expf(dotv[n]-mx); den += e[n]; }
    float rden = 1.f/den;
    float z[8];
    #pragma unroll
    for (int i = 0; i < 8; i++) z[i] = qv[i];
    #pragma unroll
    for (int n = 0; n < N_; n++) {
      float a = e[n]*rden;
      #pragma unroll
      for (int i = 0; i < 8; i++) z[i] += a*sv[n][i];
    }
    // LN1
    float sp = 0.f;
    #pragma unroll
    for (int i = 0; i < 8; i++) sp += z[i];
    float mu = gred_sum(sp) * (1.f/128.f);
    float vp = 0.f;
    #pragma unroll
    for (int i = 0; i < 8; i++) { float d0 = z[i]-mu; vp += d0*d0; }
    float var = gred_sum(vp) * (1.f/128.f);
    float rs = rsqrtf(var + 1e-5f);
    float o[8];
    #pragma unroll
    for (int i = 0; i < 8; i++) o[i] = (z[i]-mu)*rs*g1[i] + be1[i];
    float* zp = zbuf + ((size_t)b*P_ + p)*D_ + c*8;
    *(float4*)zp       = *(float4*)&o[0];
    *(float4*)(zp + 4) = *(float4*)&o[4];
  }
}

// ---------------------------------------------------------------------------
// mlp (MFMA bf16): h = gelu(z@W1+b1); y = z + h@W2+b2; LN2; transposed write.
// block: 64 points, 4 waves (16 p each). Weights streamed from L2 (B-frag order).
// ---------------------------------------------------------------------------
__global__ __launch_bounds__(256) void mlp_kernel(const float* __restrict__ zbuf,
    const unsigned short* __restrict__ w1s, const float* __restrict__ b1,
    const unsigned short* __restrict__ w2s, const float* __restrict__ b2,
    const float* __restrict__ ln2_g, const float* __restrict__ ln2_b,
    float* __restrict__ out) {
  __shared__ unsigned short zt[64*136];   // bf16 z A-tile (17408 B)
  __shared__ unsigned short ht[64*264];   // bf16 h A-tile (33792 B); reused as fp32 y[128][66]
  int tid = threadIdx.x;
  int b = blockIdx.y;
  int p0 = blockIdx.x * 64;

  // stage z tile -> bf16 LDS
  #pragma unroll
  for (int i = 0; i < 8; i++) {
    int idx = tid + i*256;           // 2048 float4 units = 64p x 32 chunks
    int pp = idx >> 5, dc = idx & 31;
    float4 v = *(const float4*)(zbuf + ((size_t)b*P_ + p0 + pp)*D_ + dc*4);
    ushort4 hh;
    hh.x = f2bf(v.x); hh.y = f2bf(v.y); hh.z = f2bf(v.z); hh.w = f2bf(v.w);
    *(ushort4*)&zt[pp*136 + dc*4] = hh;
  }
  __syncthreads();

  int ln = tid & 63, wv = tid >> 6;
  int m = ln & 15, q = ln >> 4;

  // GEMM1: rows p=wv*16+m..(16), cols 256 (16 tiles), K=128 (4 chunks)
  floatx4 a1[16];
  #pragma unroll
  for (int dt = 0; dt < 16; dt++) a1[dt] = (floatx4){0.f,0.f,0.f,0.f};
  #pragma unroll
  for (int kc = 0; kc < 4; kc++) {
    short8 af = *(const short8*)&zt[(wv*16+m)*136 + kc*32 + q*8];
    #pragma unroll
    for (int dt = 0; dt < 16; dt++) {
      short8 bfg = *(const short8*)(w1s + (((size_t)kc*16 + dt)*64 + ln)*8);
      a1[dt] = __builtin_amdgcn_mfma_f32_16x16x32_bf16(af, bfg, a1[dt], 0, 0, 0);
    }
  }
  // bias + gelu -> ht (bf16, A-frag layout rows p)
  #pragma unroll
  for (int dt = 0; dt < 16; dt++) {
    float bb = b1[dt*16 + m];
    #pragma unroll
    for (int r = 0; r < 4; r++) {
      float x = a1[dt][r] + bb;
      float hv = 0.5f*x*(1.f + erff(x*0.70710678118654752f));
      int pp = wv*16 + q*4 + r;
      ht[pp*264 + dt*16 + m] = f2bf(hv);
    }
  }
  __syncthreads();

  // GEMM2: cols 128 (8 tiles), K=256 (8 chunks)
  floatx4 a2[8];
  #pragma unroll
  for (int dt = 0; dt < 8; dt++) a2[dt] = (floatx4){0.f,0.f,0.f,0.f};
  #pragma unroll
  for (int kc = 0; kc < 8; kc++) {
    short8 af = *(const short8*)&ht[(wv*16+m)*264 + kc*32 + q*8];
    #pragma unroll
    for (int dt = 0; dt < 8; dt++) {
      short8 bfg = *(const short8*)(w2s + (((size_t)kc*8 + dt)*64 + ln)*8);
      a2[dt] = __builtin_amdgcn_mfma_f32_16x16x32_bf16(af, bfg, a2[dt], 0, 0, 0);
    }
  }
  // bias + residual
  float y[8][4];
  #pragma unroll
  for (int dt = 0; dt < 8; dt++) {
    float bb = b2[dt*16 + m];
    #pragma unroll
    for (int r = 0; r < 4; r++) {
      int pp = wv*16 + q*4 + r;
      y[dt][r] = a2[dt][r] + bb + bf2f(zt[pp*136 + dt*16 + m]);
    }
  }
  // LN2 (reduce across 16-lane group; each lane holds 8 of 128 cols per row)
  float gg[8], be[8];
  #pragma unroll
  for (int dt = 0; dt < 8; dt++) { gg[dt] = ln2_g[dt*16+m]; be[dt] = ln2_b[dt*16+m]; }
  #pragma unroll
  for (int r = 0; r < 4; r++) {
    float sp = 0.f;
    #pragma unroll
    for (int dt = 0; dt < 8; dt++) sp += y[dt][r];
    float mu = gred_sum(sp) * (1.f/128.f);
    float vp = 0.f;
    #pragma unroll
    for (int dt = 0; dt < 8; dt++) { float d0 = y[dt][r]-mu; vp += d0*d0; }
    float rs = rsqrtf(gred_sum(vp) * (1.f/128.f) + 1e-5f);
    #pragma unroll
    for (int dt = 0; dt < 8; dt++) y[dt][r] = (y[dt][r]-mu)*rs*gg[dt] + be[dt];
  }
  __syncthreads();            // all ht A-frag reads complete before overwrite
  float* yt = (float*)ht;     // y[128][66] fp32, d-major
  #pragma unroll
  for (int dt = 0; dt < 8; dt++)
    #pragma unroll
    for (int r = 0; r < 4; r++)
      yt[(dt*16 + m)*66 + wv*16 + q*4 + r] = y[dt][r];
  __syncthreads();

  // transposed cooperative write: out[b, d, p0+p]  (float2, 256B/row segments)
  #pragma unroll
  for (int i = 0; i < 16; i++) {
    int idx = tid + i*256;    // 4096 float2 units = 128 d x 32
    int d = idx >> 5, f2 = idx & 31;
    float2 v = *(float2*)&yt[d*66 + f2*2];
    *(float2*)(out + ((size_t)(b*D_ + d))*P_ + p0 + f2*2) = v;
  }
}

// ---------------------------------------------------------------------------
extern "C" void kernel_launch(void* const* d_in, const int* in_sizes, int n_in,
                              void* d_out, int out_size, void* d_ws, size_t ws_size,
                              hipStream_t stream) {
  (void)in_sizes; (void)n_in; (void)out_size; (void)ws_size;
  const float* feature   = (const float*)d_in[0];
  const float* I_src     = (const float*)d_in[1];
  const float* I_tar_inv = (const float*)d_in[2];
  const float* E         = (const float*)d_in[3];
  const float* dis       = (const float*)d_in[4];
  const float* norm_vec  = (const float*)d_in[5];
  const float* bn_gamma  = (const float*)d_in[6];
  const float* bn_beta   = (const float*)d_in[7];
  const float* bn_mean   = (const float*)d_in[8];
  const float* bn_var    = (const float*)d_in[9];
  const float* conv_w    = (const float*)d_in[10];
  const float* ln1_g     = (const float*)d_in[11];
  const float* ln1_b     = (const float*)d_in[12];
  const float* mlp_w1    = (const float*)d_in[13];
  const float* mlp_b1    = (const float*)d_in[14];
  const float* mlp_w2    = (const float*)d_in[15];
  const float* mlp_b2    = (const float*)d_in[16];
  const float* ln2_g     = (const float*)d_in[17];
  const float* ln2_b     = (const float*)d_in[18];
  float* out = (float*)d_out;

  char* ws = (char*)d_ws;
  float* bnscale       = (float*)(ws + 0);
  float* bnbias        = (float*)(ws + 1024);
  float* Hm            = (float*)(ws + 2048);
  unsigned short* wswz = (unsigned short*)(ws + 4096);      // 64 KB
  unsigned short* w1s  = (unsigned short*)(ws + 69632);     // 64 KB
  unsigned short* w2s  = (unsigned short*)(ws + 135168);    // 64 KB
  float* val  = (float*)(ws + 200704);                      // (B,N,P,D) fp32, 94.4 MB
  float* zbuf = (float*)(ws + 200704 + 94371840ULL);        // (B,P,D) fp32, 15.7 MB

  hipLaunchKernelGGL(prep_kernel, dim3(1), dim3(256), 0, stream,
                     I_src, I_tar_inv, E, dis, norm_vec,
                     bn_gamma, bn_beta, bn_mean, bn_var, bnscale, bnbias, Hm);
  hipLaunchKernelGGL(swizzle_w_kernel, dim3(128), dim3(256), 0, stream, conv_w, wswz);
  hipLaunchKernelGGL(swizzle_mlp_kernel, dim3(256), dim3(256), 0, stream,
                     mlp_w1, mlp_w2, w1s, w2s);
  hipLaunchKernelGGL(conv_kernel, dim3(120, 24), dim3(256), 0, stream,
                     feature, wswz, bnscale, bnbias, val);
  hipLaunchKernelGGL(att_kernel, dim3(240, 4), dim3(256), 0, stream,
                     val, Hm, ln1_g, ln1_b, zbuf);
  hipLaunchKernelGGL(mlp_kernel, dim3(120, 4), dim3(256), 0, stream,
                     zbuf, w1s, mlp_b1, w2s, mlp_b2, ln2_g, ln2_b, out);
}

// Round 4
// 374.404 us; speedup vs baseline: 1.5202x; 1.1476x over previous
//
#include <hip/hip_runtime.h>
#include <hip/hip_bf16.h>
#include <math.h>

#define B_ 4
#define N_ 6
#define FD_ 256
#define D_ 128
#define HF_ 64
#define WF_ 120
#define P_ (HF_*WF_)   // 7680

typedef __attribute__((ext_vector_type(8))) short short8;
typedef __attribute__((ext_vector_type(4))) float floatx4;
typedef __attribute__((ext_vector_type(4))) unsigned int uint4e;

__device__ inline float gred_sum(float v) {   // sum within 16-lane group
  v += __shfl_xor(v, 1); v += __shfl_xor(v, 2);
  v += __shfl_xor(v, 4); v += __shfl_xor(v, 8);
  return v;
}

__device__ inline unsigned short f2bf(float f) {
  unsigned int u = __builtin_bit_cast(unsigned int, f);
  u += 0x7fffu + ((u >> 16) & 1u);   // RNE
  return (unsigned short)(u >> 16);
}
__device__ inline float bf2f(unsigned short h) {
  return __builtin_bit_cast(float, ((unsigned int)h) << 16);
}
// unpack a dword holding two bf16 (lo = even elem, hi = odd elem)
__device__ inline void bfu2(unsigned int u, float& lo, float& hi) {
  lo = __builtin_bit_cast(float, u << 16);
  hi = __builtin_bit_cast(float, u & 0xffff0000u);
}

// ---------------------------------------------------------------------------
// prep: BN scale/bias folding + homography matrices
// ---------------------------------------------------------------------------
__global__ void prep_kernel(const float* __restrict__ I_src, const float* __restrict__ I_tar_inv,
                            const float* __restrict__ E, const float* __restrict__ dis,
                            const float* __restrict__ norm_vec,
                            const float* __restrict__ bn_gamma, const float* __restrict__ bn_beta,
                            const float* __restrict__ bn_mean, const float* __restrict__ bn_var,
                            float* __restrict__ bnscale, float* __restrict__ bnbias,
                            float* __restrict__ Hm) {
  int t = threadIdx.x;
  if (t < FD_) {
    float s = bn_gamma[t] * rsqrtf(bn_var[t] + 1e-5f);
    bnscale[t] = s;
    bnbias[t] = bn_beta[t] - bn_mean[t] * s;
  }
  if (t < B_*N_) {
    int b = t / N_;
    const float* e = E + t*16;
    const float* nv = norm_vec + b*3;
    float inv_dis = 1.0f / dis[0];
    float M[9];
    #pragma unroll
    for (int r = 0; r < 3; r++)
      #pragma unroll
      for (int c = 0; c < 3; c++)
        M[r*3+c] = e[r*4+c] - e[r*4+3]*nv[c]*inv_dis;
    const float* Is = I_src + t*9;
    float A[9];
    #pragma unroll
    for (int r = 0; r < 3; r++)
      #pragma unroll
      for (int c = 0; c < 3; c++)
        A[r*3+c] = Is[r*3+0]*M[0*3+c] + Is[r*3+1]*M[1*3+c] + Is[r*3+2]*M[2*3+c];
    const float* It = I_tar_inv + b*9;
    #pragma unroll
    for (int r = 0; r < 3; r++)
      #pragma unroll
      for (int c = 0; c < 3; c++)
        Hm[t*9 + r*3+c] = A[r*3+0]*It[0*3+c] + A[r*3+1]*It[1*3+c] + A[r*3+2]*It[2*3+c];
  }
}

// ---------------------------------------------------------------------------
// swizzle conv_w (D,FD) fp32 -> bf16 B-fragment order (t = ((kc*8+dt)*64+ln)*8+j)
// ---------------------------------------------------------------------------
__global__ void swizzle_w_kernel(const float* __restrict__ conv_w, unsigned short* __restrict__ wswz) {
  int t = blockIdx.x * 256 + threadIdx.x;   // 0..32767
  int j    =  t        & 7;
  int lane = (t >> 3)  & 63;
  int dt   = (t >> 9)  & 7;
  int kc   =  t >> 12;
  int d = dt*16 + (lane & 15);
  int k = kc*32 + (lane >> 4)*8 + j;
  wswz[t] = f2bf(conv_w[d*FD_ + k]);
}

// ---------------------------------------------------------------------------
// swizzle mlp weights to B-frag order bf16
// ---------------------------------------------------------------------------
__global__ void swizzle_mlp_kernel(const float* __restrict__ w1, const float* __restrict__ w2,
                                   unsigned short* __restrict__ w1s, unsigned short* __restrict__ w2s) {
  int t = blockIdx.x * 256 + threadIdx.x;   // 0..65535
  if (t < 32768) {
    int j    =  t        & 7;
    int lane = (t >> 3)  & 63;
    int dt   = (t >> 9)  & 15;
    int kc   =  t >> 13;
    int n = dt*16 + (lane & 15);
    int k = kc*32 + (lane >> 4)*8 + j;
    w1s[t] = f2bf(w1[k*256 + n]);
  } else {
    int u = t - 32768;
    int j    =  u        & 7;
    int lane = (u >> 3)  & 63;
    int dt   = (u >> 9)  & 7;
    int kc   =  u >> 12;
    int n = dt*16 + (lane & 15);
    int k = kc*32 + (lane >> 4)*8 + j;
    w2s[u] = f2bf(w2[k*128 + n]);
  }
}

// ---------------------------------------------------------------------------
// conv (MFMA): coalesced dwordx4 feature loads along p, LDS transpose
// (k-pair packed b32 writes, stride 36), double-buffered, B-frags from L2.
// block: 64 p x 128 d, 4 waves (16 p each). val output bf16 via LDS epilogue.
// ---------------------------------------------------------------------------
__global__ __launch_bounds__(256) void conv_kernel(const float* __restrict__ feature,
    const unsigned short* __restrict__ wswz, const float* __restrict__ bnscale,
    const float* __restrict__ bnbias, unsigned short* __restrict__ val) {
  __shared__ unsigned short apad[2][64*36];   // 2 x 4608 B
  __shared__ unsigned short ytile[64*136];    // 17408 B
  __shared__ float sbn[512];

  int tid = threadIdx.x;
  if (tid < 256) { sbn[tid] = bnscale[tid]; sbn[256+tid] = bnbias[tid]; }

  int bn = blockIdx.y;
  int p0 = blockIdx.x * 64;
  const float* fbase2 = feature + (size_t)bn*FD_*P_ + p0;

  int K0 = tid >> 4;   // 0..15 (k-pair index within chunk)
  int pc = tid & 15;   // 16-B p-group
  int sp = pc*4;

  int ln = tid & 63, wv = tid >> 6;
  int m = ln & 15, q = ln >> 4;
  int row = wv*16 + m;

  auto stage = [&](int kc, int bb) {
    int k0 = kc*32;
    const float* fb = fbase2 + (size_t)(k0 + 2*K0)*P_ + sp;
    float4 v0 = *(const float4*)fb;
    float4 v1 = *(const float4*)(fb + P_);
    float s0 = sbn[k0+2*K0],   b0 = sbn[256+k0+2*K0];
    float s1 = sbn[k0+2*K0+1], b1 = sbn[256+k0+2*K0+1];
    float a0[4] = {v0.x, v0.y, v0.z, v0.w};
    float a1[4] = {v1.x, v1.y, v1.z, v1.w};
    #pragma unroll
    for (int i = 0; i < 4; i++) {
      unsigned int w = (unsigned int)f2bf(fmaxf(a0[i]*s0+b0, 0.f))
                     | ((unsigned int)f2bf(fmaxf(a1[i]*s1+b1, 0.f)) << 16);
      *(unsigned int*)&apad[bb][(sp+i)*36 + 2*K0] = w;
    }
  };

  floatx4 acc[8];
  #pragma unroll
  for (int dt = 0; dt < 8; dt++) acc[dt] = (floatx4){0.f,0.f,0.f,0.f};

  stage(0, 0);
  __syncthreads();

  for (int kc = 0; kc < 8; kc++) {
    int bb = kc & 1;
    if (kc < 7) stage(kc+1, bb ^ 1);
    // A-frag from LDS (2 x ds_read_b64)
    uint2 u0 = *(const uint2*)&apad[bb][row*36 + q*8];
    uint2 u1 = *(const uint2*)&apad[bb][row*36 + q*8 + 4];
    uint4e ua = {u0.x, u0.y, u1.x, u1.y};
    short8 af = __builtin_bit_cast(short8, ua);
    #pragma unroll
    for (int dt = 0; dt < 8; dt++) {
      short8 bfg = *(const short8*)(wswz + (((size_t)kc*8 + dt)*64 + ln)*8);
      acc[dt] = __builtin_amdgcn_mfma_f32_16x16x32_bf16(af, bfg, acc[dt], 0, 0, 0);
    }
    if (kc < 7) __syncthreads();
  }

  // epilogue: C/D col = lane&15 (d), row = quad*4+reg (p); bf16 via LDS
  #pragma unroll
  for (int dt = 0; dt < 8; dt++)
    #pragma unroll
    for (int r = 0; r < 4; r++)
      ytile[(wv*16 + q*4 + r)*136 + dt*16 + m] = f2bf(acc[dt][r]);
  __syncthreads();
  #pragma unroll
  for (int i = 0; i < 4; i++) {
    int idx = tid + i*256;          // 1024 = 64 p x 16 chunks of 8 d
    int pp = idx >> 4, ch = idx & 15;
    uint4 v = *(const uint4*)&ytile[pp*136 + ch*8];
    *(uint4*)(val + ((size_t)bn*P_ + p0 + pp)*D_ + ch*8) = v;
  }
}

// ---------------------------------------------------------------------------
// att: 16-lane group per point (8 vals/lane), bf16 val gathers.
// ---------------------------------------------------------------------------
__global__ __launch_bounds__(256) void att_kernel(const unsigned short* __restrict__ val,
    const float* __restrict__ Hm, const float* __restrict__ ln1_g,
    const float* __restrict__ ln1_b, unsigned short* __restrict__ zbuf) {
  int b = blockIdx.y;
  int p0 = blockIdx.x * 32;
  int tid = threadIdx.x;
  int ln = tid & 63, wv = tid >> 6;
  int grp = ln >> 4, c = ln & 15;   // lane's d-range: c*8 .. c*8+7

  float g1[8], be1[8];
  *(float4*)&g1[0]  = *(const float4*)(ln1_g + c*8);
  *(float4*)&g1[4]  = *(const float4*)(ln1_g + c*8 + 4);
  *(float4*)&be1[0] = *(const float4*)(ln1_b + c*8);
  *(float4*)&be1[4] = *(const float4*)(ln1_b + c*8 + 4);

  for (int pi = 0; pi < 2; pi++) {
    int p = p0 + wv*8 + grp*2 + pi;
    int py = p / WF_, px = p - py*WF_;
    float pixx = (float)px * (960.f/119.f);
    float pixy = (float)py * (480.f/63.f);

    const unsigned short* qptr = val + ((size_t)(b*N_)*P_ + p)*D_ + c*8;
    uint4 qu = *(const uint4*)qptr;
    float qv[8];
    bfu2(qu.x, qv[0], qv[1]); bfu2(qu.y, qv[2], qv[3]);
    bfu2(qu.z, qv[4], qv[5]); bfu2(qu.w, qv[6], qv[7]);
    float qp = 0.f;
    #pragma unroll
    for (int i = 0; i < 8; i++) qp += qv[i]*qv[i];
    float qinv = 1.f / fmaxf(sqrtf(gred_sum(qp)), 1e-12f);

    float dotv[N_];
    float sv[N_][8];
    #pragma unroll
    for (int n = 0; n < N_; n++) {
      const float* H = Hm + (b*N_+n)*9;
      float hx = H[0]*pixx + H[1]*pixy + H[2];
      float hy = H[3]*pixx + H[4]*pixy + H[5];
      float hz = H[6]*pixx + H[7]*pixy + H[8];
      float sx = (hx/hz) * ((float)WF_/960.f);
      float sy = (hy/hz) * ((float)HF_/480.f);
      float x0f = floorf(sx), y0f = floorf(sy);
      float fx = sx - x0f, fy = sy - y0f;
      int x0 = (int)x0f, y0 = (int)y0f;
      const unsigned short* base = val + ((size_t)(b*N_+n)*P_)*D_ + c*8;
      float acc[8];
      #pragma unroll
      for (int i = 0; i < 8; i++) acc[i] = 0.f;
      #pragma unroll
      for (int dy = 0; dy < 2; dy++) {
        #pragma unroll
        for (int dx = 0; dx < 2; dx++) {
          int cx = x0 + dx, cy = y0 + dy;
          float wgt = (dx ? fx : 1.f-fx) * (dy ? fy : 1.f-fy);
          bool inb = (cx >= 0) && (cx <= WF_-1) && (cy >= 0) && (cy <= HF_-1);
          int icx = min(max(cx,0),WF_-1), icy = min(max(cy,0),HF_-1);
          uint4 gu = *(const uint4*)(base + (size_t)(icy*WF_ + icx)*D_);
          float g[8];
          bfu2(gu.x, g[0], g[1]); bfu2(gu.y, g[2], g[3]);
          bfu2(gu.z, g[4], g[5]); bfu2(gu.w, g[6], g[7]);
          float wm = inb ? wgt : 0.f;
          #pragma unroll
          for (int i = 0; i < 8; i++) acc[i] += g[i]*wm;
        }
      }
      float ssp = 0.f, qsp = 0.f;
      #pragma unroll
      for (int i = 0; i < 8; i++) { ssp += acc[i]*acc[i]; qsp += qv[i]*acc[i]; }
      float ss = gred_sum(ssp);
      float qs = gred_sum(qsp);
      float dn = qs * qinv / fmaxf(sqrtf(ss), 1e-12f);
      bool valid = (sx >= 0.f) && (sx <= (float)(WF_-1)) && (sy >= 0.f) && (sy <= (float)(HF_-1));
      dotv[n] = valid ? dn : 0.f;
      #pragma unroll
      for (int i = 0; i < 8; i++) sv[n][i] = acc[i];
    }
    float mx = dotv[0];
    #pragma unroll
    for (int n = 1; n < N_; n++) mx = fmaxf(mx, dotv[n]);
    float e[N_]; float den = 0.f;
    #pragma unroll
    for (int n = 0; n < N_; n++) { e[n] = expf(dotv[n]-mx); den += e[n]; }
    float rden = 1.f/den;
    float z[8];
    #pragma unroll
    for (int i = 0; i < 8; i++) z[i] = qv[i];
    #pragma unroll
    for (int n = 0; n < N_; n++) {
      float a = e[n]*rden;
      #pragma unroll
      for (int i = 0; i < 8; i++) z[i] += a*sv[n][i];
    }
    // LN1
    float sp = 0.f;
    #pragma unroll
    for (int i = 0; i < 8; i++) sp += z[i];
    float mu = gred_sum(sp) * (1.f/128.f);
    float vp = 0.f;
    #pragma unroll
    for (int i = 0; i < 8; i++) { float d0 = z[i]-mu; vp += d0*d0; }
    float var = gred_sum(vp) * (1.f/128.f);
    float rs = rsqrtf(var + 1e-5f);
    unsigned int ow[4];
    #pragma unroll
    for (int i = 0; i < 4; i++) {
      float o0 = (z[2*i]-mu)*rs*g1[2*i] + be1[2*i];
      float o1 = (z[2*i+1]-mu)*rs*g1[2*i+1] + be1[2*i+1];
      ow[i] = (unsigned int)f2bf(o0) | ((unsigned int)f2bf(o1) << 16);
    }
    uint4 ov = make_uint4(ow[0], ow[1], ow[2], ow[3]);
    *(uint4*)(zbuf + ((size_t)b*P_ + p)*D_ + c*8) = ov;
  }
}

// ---------------------------------------------------------------------------
// mlp (MFMA bf16): h = gelu(z@W1+b1); y = z + h@W2+b2; LN2; transposed write.
// block: 64 points, 4 waves. zbuf is bf16 (direct A-tile staging).
// ---------------------------------------------------------------------------
__global__ __launch_bounds__(256) void mlp_kernel(const unsigned short* __restrict__ zbuf,
    const unsigned short* __restrict__ w1s, const float* __restrict__ b1,
    const unsigned short* __restrict__ w2s, const float* __restrict__ b2,
    const float* __restrict__ ln2_g, const float* __restrict__ ln2_b,
    float* __restrict__ out) {
  __shared__ unsigned short zt[64*136];   // bf16 z A-tile (17408 B)
  __shared__ unsigned short ht[64*264];   // bf16 h A-tile (33792 B); reused as fp32 y[128][66]
  int tid = threadIdx.x;
  int b = blockIdx.y;
  int p0 = blockIdx.x * 64;

  // stage z tile (already bf16)
  #pragma unroll
  for (int i = 0; i < 4; i++) {
    int idx = tid + i*256;           // 1024 = 64 p x 16 chunks of 8 d
    int pp = idx >> 4, ch = idx & 15;
    uint4 v = *(const uint4*)(zbuf + ((size_t)b*P_ + p0 + pp)*D_ + ch*8);
    *(uint4*)&zt[pp*136 + ch*8] = v;
  }
  __syncthreads();

  int ln = tid & 63, wv = tid >> 6;
  int m = ln & 15, q = ln >> 4;

  // GEMM1: K=128 (4 chunks), cols 256 (16 tiles)
  floatx4 a1[16];
  #pragma unroll
  for (int dt = 0; dt < 16; dt++) a1[dt] = (floatx4){0.f,0.f,0.f,0.f};
  #pragma unroll
  for (int kc = 0; kc < 4; kc++) {
    short8 af = *(const short8*)&zt[(wv*16+m)*136 + kc*32 + q*8];
    #pragma unroll
    for (int dt = 0; dt < 16; dt++) {
      short8 bfg = *(const short8*)(w1s + (((size_t)kc*16 + dt)*64 + ln)*8);
      a1[dt] = __builtin_amdgcn_mfma_f32_16x16x32_bf16(af, bfg, a1[dt], 0, 0, 0);
    }
  }
  // bias + gelu -> ht
  #pragma unroll
  for (int dt = 0; dt < 16; dt++) {
    float bb = b1[dt*16 + m];
    #pragma unroll
    for (int r = 0; r < 4; r++) {
      float x = a1[dt][r] + bb;
      float hv = 0.5f*x*(1.f + erff(x*0.70710678118654752f));
      int pp = wv*16 + q*4 + r;
      ht[pp*264 + dt*16 + m] = f2bf(hv);
    }
  }
  __syncthreads();

  // GEMM2: K=256 (8 chunks), cols 128 (8 tiles)
  floatx4 a2[8];
  #pragma unroll
  for (int dt = 0; dt < 8; dt++) a2[dt] = (floatx4){0.f,0.f,0.f,0.f};
  #pragma unroll
  for (int kc = 0; kc < 8; kc++) {
    short8 af = *(const short8*)&ht[(wv*16+m)*264 + kc*32 + q*8];
    #pragma unroll
    for (int dt = 0; dt < 8; dt++) {
      short8 bfg = *(const short8*)(w2s + (((size_t)kc*8 + dt)*64 + ln)*8);
      a2[dt] = __builtin_amdgcn_mfma_f32_16x16x32_bf16(af, bfg, a2[dt], 0, 0, 0);
    }
  }
  // bias + residual
  float y[8][4];
  #pragma unroll
  for (int dt = 0; dt < 8; dt++) {
    float bb = b2[dt*16 + m];
    #pragma unroll
    for (int r = 0; r < 4; r++) {
      int pp = wv*16 + q*4 + r;
      y[dt][r] = a2[dt][r] + bb + bf2f(zt[pp*136 + dt*16 + m]);
    }
  }
  // LN2
  float gg[8], be[8];
  #pragma unroll
  for (int dt = 0; dt < 8; dt++) { gg[dt] = ln2_g[dt*16+m]; be[dt] = ln2_b[dt*16+m]; }
  #pragma unroll
  for (int r = 0; r < 4; r++) {
    float sp = 0.f;
    #pragma unroll
    for (int dt = 0; dt < 8; dt++) sp += y[dt][r];
    float mu = gred_sum(sp) * (1.f/128.f);
    float vp = 0.f;
    #pragma unroll
    for (int dt = 0; dt < 8; dt++) { float d0 = y[dt][r]-mu; vp += d0*d0; }
    float rs = rsqrtf(gred_sum(vp) * (1.f/128.f) + 1e-5f);
    #pragma unroll
    for (int dt = 0; dt < 8; dt++) y[dt][r] = (y[dt][r]-mu)*rs*gg[dt] + be[dt];
  }
  __syncthreads();
  float* yt = (float*)ht;     // y[128][66] fp32, d-major
  #pragma unroll
  for (int dt = 0; dt < 8; dt++)
    #pragma unroll
    for (int r = 0; r < 4; r++)
      yt[(dt*16 + m)*66 + wv*16 + q*4 + r] = y[dt][r];
  __syncthreads();

  // transposed cooperative write: out[b, d, p0+p]
  #pragma unroll
  for (int i = 0; i < 16; i++) {
    int idx = tid + i*256;    // 4096 float2 units = 128 d x 32
    int d = idx >> 5, f2 = idx & 31;
    float2 v = *(float2*)&yt[d*66 + f2*2];
    *(float2*)(out + ((size_t)(b*D_ + d))*P_ + p0 + f2*2) = v;
  }
}

// ---------------------------------------------------------------------------
extern "C" void kernel_launch(void* const* d_in, const int* in_sizes, int n_in,
                              void* d_out, int out_size, void* d_ws, size_t ws_size,
                              hipStream_t stream) {
  (void)in_sizes; (void)n_in; (void)out_size; (void)ws_size;
  const float* feature   = (const float*)d_in[0];
  const float* I_src     = (const float*)d_in[1];
  const float* I_tar_inv = (const float*)d_in[2];
  const float* E         = (const float*)d_in[3];
  const float* dis       = (const float*)d_in[4];
  const float* norm_vec  = (const float*)d_in[5];
  const float* bn_gamma  = (const float*)d_in[6];
  const float* bn_beta   = (const float*)d_in[7];
  const float* bn_mean   = (const float*)d_in[8];
  const float* bn_var    = (const float*)d_in[9];
  const float* conv_w    = (const float*)d_in[10];
  const float* ln1_g     = (const float*)d_in[11];
  const float* ln1_b     = (const float*)d_in[12];
  const float* mlp_w1    = (const float*)d_in[13];
  const float* mlp_b1    = (const float*)d_in[14];
  const float* mlp_w2    = (const float*)d_in[15];
  const float* mlp_b2    = (const float*)d_in[16];
  const float* ln2_g     = (const float*)d_in[17];
  const float* ln2_b     = (const float*)d_in[18];
  float* out = (float*)d_out;

  char* ws = (char*)d_ws;
  float* bnscale       = (float*)(ws + 0);
  float* bnbias        = (float*)(ws + 1024);
  float* Hm            = (float*)(ws + 2048);
  unsigned short* wswz = (unsigned short*)(ws + 4096);      // 64 KB
  unsigned short* w1s  = (unsigned short*)(ws + 69632);     // 64 KB
  unsigned short* w2s  = (unsigned short*)(ws + 135168);    // 64 KB
  unsigned short* val  = (unsigned short*)(ws + 200704);              // (B,N,P,D) bf16, 47.2 MB
  unsigned short* zbuf = (unsigned short*)(ws + 200704 + 47185920ULL);// (B,P,D) bf16, 7.9 MB

  hipLaunchKernelGGL(prep_kernel, dim3(1), dim3(256), 0, stream,
                     I_src, I_tar_inv, E, dis, norm_vec,
                     bn_gamma, bn_beta, bn_mean, bn_var, bnscale, bnbias, Hm);
  hipLaunchKernelGGL(swizzle_w_kernel, dim3(128), dim3(256), 0, stream, conv_w, wswz);
  hipLaunchKernelGGL(swizzle_mlp_kernel, dim3(256), dim3(256), 0, stream,
                     mlp_w1, mlp_w2, w1s, w2s);
  hipLaunchKernelGGL(conv_kernel, dim3(120, 24), dim3(256), 0, stream,
                     feature, wswz, bnscale, bnbias, val);
  hipLaunchKernelGGL(att_kernel, dim3(240, 4), dim3(256), 0, stream,
                     val, Hm, ln1_g, ln1_b, zbuf);
  hipLaunchKernelGGL(mlp_kernel, dim3(120, 4), dim3(256), 0, stream,
                     zbuf, w1s, mlp_b1, w2s, mlp_b2, ln2_g, ln2_b, out);
}

// Round 5
// 369.144 us; speedup vs baseline: 1.5418x; 1.0142x over previous
//
#include <hip/hip_runtime.h>
#include <hip/hip_bf16.h>
#include <math.h>

#define B_ 4
#define N_ 6
#define FD_ 256
#define D_ 128
#define HF_ 64
#define WF_ 120
#define P_ (HF_*WF_)   // 7680

typedef __attribute__((ext_vector_type(8))) short short8;
typedef __attribute__((ext_vector_type(4))) float floatx4;
typedef __attribute__((ext_vector_type(4))) unsigned int uint4e;

__device__ inline float gred_sum(float v) {   // sum within 16-lane group
  v += __shfl_xor(v, 1); v += __shfl_xor(v, 2);
  v += __shfl_xor(v, 4); v += __shfl_xor(v, 8);
  return v;
}

__device__ inline unsigned short f2bf(float f) {
  unsigned int u = __builtin_bit_cast(unsigned int, f);
  u += 0x7fffu + ((u >> 16) & 1u);   // RNE
  return (unsigned short)(u >> 16);
}
__device__ inline float bf2f(unsigned short h) {
  return __builtin_bit_cast(float, ((unsigned int)h) << 16);
}
__device__ inline void bfu2(unsigned int u, float& lo, float& hi) {
  lo = __builtin_bit_cast(float, u << 16);
  hi = __builtin_bit_cast(float, u & 0xffff0000u);
}

// ---------------------------------------------------------------------------
// prep: BN fold + homographies
// ---------------------------------------------------------------------------
__global__ void prep_kernel(const float* __restrict__ I_src, const float* __restrict__ I_tar_inv,
                            const float* __restrict__ E, const float* __restrict__ dis,
                            const float* __restrict__ norm_vec,
                            const float* __restrict__ bn_gamma, const float* __restrict__ bn_beta,
                            const float* __restrict__ bn_mean, const float* __restrict__ bn_var,
                            float* __restrict__ bnscale, float* __restrict__ bnbias,
                            float* __restrict__ Hm) {
  int t = threadIdx.x;
  if (t < FD_) {
    float s = bn_gamma[t] * rsqrtf(bn_var[t] + 1e-5f);
    bnscale[t] = s;
    bnbias[t] = bn_beta[t] - bn_mean[t] * s;
  }
  if (t < B_*N_) {
    int b = t / N_;
    const float* e = E + t*16;
    const float* nv = norm_vec + b*3;
    float inv_dis = 1.0f / dis[0];
    float M[9];
    #pragma unroll
    for (int r = 0; r < 3; r++)
      #pragma unroll
      for (int c = 0; c < 3; c++)
        M[r*3+c] = e[r*4+c] - e[r*4+3]*nv[c]*inv_dis;
    const float* Is = I_src + t*9;
    float A[9];
    #pragma unroll
    for (int r = 0; r < 3; r++)
      #pragma unroll
      for (int c = 0; c < 3; c++)
        A[r*3+c] = Is[r*3+0]*M[0*3+c] + Is[r*3+1]*M[1*3+c] + Is[r*3+2]*M[2*3+c];
    const float* It = I_tar_inv + b*9;
    #pragma unroll
    for (int r = 0; r < 3; r++)
      #pragma unroll
      for (int c = 0; c < 3; c++)
        Hm[t*9 + r*3+c] = A[r*3+0]*It[0*3+c] + A[r*3+1]*It[1*3+c] + A[r*3+2]*It[2*3+c];
  }
}

// ---------------------------------------------------------------------------
// uv precompute: sx,sy per (b,n,p). 184320 = 720*256 exactly.
// ---------------------------------------------------------------------------
__global__ void uv_kernel(const float* __restrict__ Hm, float2* __restrict__ uvbuf) {
  int t = blockIdx.x * 256 + threadIdx.x;
  int p  = t % P_;
  int bn = t / P_;
  int py = p / WF_, px = p - py*WF_;
  float pixx = (float)px * (960.f/119.f);
  float pixy = (float)py * (480.f/63.f);
  const float* H = Hm + bn*9;
  float hx = H[0]*pixx + H[1]*pixy + H[2];
  float hy = H[3]*pixx + H[4]*pixy + H[5];
  float hz = H[6]*pixx + H[7]*pixy + H[8];
  float sx = (hx/hz) * ((float)WF_/960.f);
  float sy = (hy/hz) * ((float)HF_/480.f);
  uvbuf[t] = make_float2(sx, sy);
}

// ---------------------------------------------------------------------------
// swizzle conv_w (D,FD) fp32 -> bf16 B-fragment order
// ---------------------------------------------------------------------------
__global__ void swizzle_w_kernel(const float* __restrict__ conv_w, unsigned short* __restrict__ wswz) {
  int t = blockIdx.x * 256 + threadIdx.x;   // 0..32767
  int j    =  t        & 7;
  int lane = (t >> 3)  & 63;
  int dt   = (t >> 9)  & 7;
  int kc   =  t >> 12;
  int d = dt*16 + (lane & 15);
  int k = kc*32 + (lane >> 4)*8 + j;
  wswz[t] = f2bf(conv_w[d*FD_ + k]);
}

// ---------------------------------------------------------------------------
// swizzle mlp weights to B-frag order bf16
// ---------------------------------------------------------------------------
__global__ void swizzle_mlp_kernel(const float* __restrict__ w1, const float* __restrict__ w2,
                                   unsigned short* __restrict__ w1s, unsigned short* __restrict__ w2s) {
  int t = blockIdx.x * 256 + threadIdx.x;   // 0..65535
  if (t < 32768) {
    int j    =  t        & 7;
    int lane = (t >> 3)  & 63;
    int dt   = (t >> 9)  & 15;
    int kc   =  t >> 13;
    int n = dt*16 + (lane & 15);
    int k = kc*32 + (lane >> 4)*8 + j;
    w1s[t] = f2bf(w1[k*256 + n]);
  } else {
    int u = t - 32768;
    int j    =  u        & 7;
    int lane = (u >> 3)  & 63;
    int dt   = (u >> 9)  & 7;
    int kc   =  u >> 12;
    int n = dt*16 + (lane & 15);
    int k = kc*32 + (lane >> 4)*8 + j;
    w2s[u] = f2bf(w2[k*128 + n]);
  }
}

// ---------------------------------------------------------------------------
// conv (MFMA): depth-2 register prefetch (loads live across the barrier),
// LDS double-buffer, ytile aliases apad (19.4 KB LDS -> 8 blocks/CU).
// block: 64 p x 128 d, 4 waves.
// ---------------------------------------------------------------------------
#define AST_ 36   // apad stride in shorts (72 B rows, 8B-aligned frag reads)
__global__ __launch_bounds__(256) void conv_kernel(const float* __restrict__ feature,
    const unsigned short* __restrict__ wswz, const float* __restrict__ bnscale,
    const float* __restrict__ bnbias, unsigned short* __restrict__ val) {
  __shared__ __align__(16) char csm[19968];
  unsigned short* apadA = (unsigned short*)csm;            // 64*36*2 = 4608 B
  unsigned short* apadB = (unsigned short*)(csm + 4608);   // 4608 B
  unsigned short* ytile = (unsigned short*)csm;            // 64*136*2 = 17408 B (alias)
  float* sbn = (float*)(csm + 17408);                      // 2048 B

  int tid = threadIdx.x;
  sbn[tid] = bnscale[tid]; sbn[256+tid] = bnbias[tid];

  int bn = blockIdx.y;
  int p0 = blockIdx.x * 64;
  const float* fbase2 = feature + (size_t)bn*FD_*P_ + p0;

  int K0 = tid >> 4;   // k-pair index within chunk
  int sp = (tid & 15) * 4;

  int ln = tid & 63, wv = tid >> 6;
  int m = ln & 15, q = ln >> 4;
  int row = wv*16 + m;

  float4 va[2], vb[2];
  // prolog loads: chunks 0,1
  {
    const float* fb0 = fbase2 + (size_t)(2*K0)*P_ + sp;
    va[0] = *(const float4*)fb0; vb[0] = *(const float4*)(fb0 + P_);
    const float* fb1 = fbase2 + (size_t)(32 + 2*K0)*P_ + sp;
    va[1] = *(const float4*)fb1; vb[1] = *(const float4*)(fb1 + P_);
  }
  __syncthreads();   // sbn visible

  floatx4 acc[8];
  #pragma unroll
  for (int dt = 0; dt < 8; dt++) acc[dt] = (floatx4){0.f,0.f,0.f,0.f};

  // pack chunk0 -> apadA
  {
    int k0 = 0;
    float s0 = sbn[k0+2*K0],   b0 = sbn[256+k0+2*K0];
    float s1 = sbn[k0+2*K0+1], b1 = sbn[256+k0+2*K0+1];
    float a0[4] = {va[0].x, va[0].y, va[0].z, va[0].w};
    float a1[4] = {vb[0].x, vb[0].y, vb[0].z, vb[0].w};
    #pragma unroll
    for (int i = 0; i < 4; i++) {
      unsigned int w = (unsigned int)f2bf(fmaxf(a0[i]*s0+b0, 0.f))
                     | ((unsigned int)f2bf(fmaxf(a1[i]*s1+b1, 0.f)) << 16);
      *(unsigned int*)&apadA[(sp+i)*AST_ + 2*K0] = w;
    }
  }

  #pragma unroll
  for (int kc = 0; kc < 8; kc++) {
    __syncthreads();
    // issue loads for chunk kc+2 (stay in flight across this whole iteration)
    if (kc + 2 < 8) {
      const float* fb = fbase2 + (size_t)((kc+2)*32 + 2*K0)*P_ + sp;
      va[kc&1] = *(const float4*)fb;
      vb[kc&1] = *(const float4*)(fb + P_);
    }
    // pack+write chunk kc+1 (its loads were issued a full iteration ago)
    if (kc + 1 < 8) {
      int s = (kc+1)&1;
      int k0 = (kc+1)*32;
      unsigned short* ap = ((kc+1)&1) ? apadB : apadA;
      float s0 = sbn[k0+2*K0],   b0 = sbn[256+k0+2*K0];
      float s1 = sbn[k0+2*K0+1], b1 = sbn[256+k0+2*K0+1];
      float a0[4] = {va[s].x, va[s].y, va[s].z, va[s].w};
      float a1[4] = {vb[s].x, vb[s].y, vb[s].z, vb[s].w};
      #pragma unroll
      for (int i = 0; i < 4; i++) {
        unsigned int w = (unsigned int)f2bf(fmaxf(a0[i]*s0+b0, 0.f))
                       | ((unsigned int)f2bf(fmaxf(a1[i]*s1+b1, 0.f)) << 16);
        *(unsigned int*)&ap[(sp+i)*AST_ + 2*K0] = w;
      }
    }
    // MFMA chunk kc
    unsigned short* rp = (kc&1) ? apadB : apadA;
    uint2 u0 = *(const uint2*)&rp[row*AST_ + q*8];
    uint2 u1 = *(const uint2*)&rp[row*AST_ + q*8 + 4];
    uint4e ua = {u0.x, u0.y, u1.x, u1.y};
    short8 af = __builtin_bit_cast(short8, ua);
    #pragma unroll
    for (int dt = 0; dt < 8; dt++) {
      short8 bfg = *(const short8*)(wswz + (((size_t)kc*8 + dt)*64 + ln)*8);
      acc[dt] = __builtin_amdgcn_mfma_f32_16x16x32_bf16(af, bfg, acc[dt], 0, 0, 0);
    }
  }
  __syncthreads();   // all apad reads done before ytile alias writes

  #pragma unroll
  for (int dt = 0; dt < 8; dt++)
    #pragma unroll
    for (int r = 0; r < 4; r++)
      ytile[(wv*16 + q*4 + r)*136 + dt*16 + m] = f2bf(acc[dt][r]);
  __syncthreads();
  #pragma unroll
  for (int i = 0; i < 4; i++) {
    int idx = tid + i*256;
    int pp = idx >> 4, ch = idx & 15;
    uint4 v = *(const uint4*)&ytile[pp*136 + ch*8];
    *(uint4*)(val + ((size_t)bn*P_ + p0 + pp)*D_ + ch*8) = v;
  }
}

// ---------------------------------------------------------------------------
// att: 16-lane group per point, uv precomputed, gathers issued in n-pairs
// ahead of math for memory-level parallelism.
// ---------------------------------------------------------------------------
__global__ __launch_bounds__(256) void att_kernel(const unsigned short* __restrict__ val,
    const float2* __restrict__ uvbuf, const float* __restrict__ ln1_g,
    const float* __restrict__ ln1_b, unsigned short* __restrict__ zbuf) {
  int b = blockIdx.y;
  int p0 = blockIdx.x * 32;
  int tid = threadIdx.x;
  int ln = tid & 63, wv = tid >> 6;
  int grp = ln >> 4, c = ln & 15;

  float g1[8], be1[8];
  *(float4*)&g1[0]  = *(const float4*)(ln1_g + c*8);
  *(float4*)&g1[4]  = *(const float4*)(ln1_g + c*8 + 4);
  *(float4*)&be1[0] = *(const float4*)(ln1_b + c*8);
  *(float4*)&be1[4] = *(const float4*)(ln1_b + c*8 + 4);

  for (int pi = 0; pi < 2; pi++) {
    int p = p0 + wv*8 + grp*2 + pi;

    uint4 qu = *(const uint4*)(val + ((size_t)(b*N_)*P_ + p)*D_ + c*8);
    float qv[8];
    bfu2(qu.x, qv[0], qv[1]); bfu2(qu.y, qv[2], qv[3]);
    bfu2(qu.z, qv[4], qv[5]); bfu2(qu.w, qv[6], qv[7]);
    float qp = 0.f;
    #pragma unroll
    for (int i = 0; i < 8; i++) qp += qv[i]*qv[i];
    float qinv = 1.f / fmaxf(sqrtf(gred_sum(qp)), 1e-12f);

    float dotv[N_];
    float sv[N_][8];
    #pragma unroll
    for (int np = 0; np < 3; np++) {
      uint4 g[2][4]; float wm[2][4]; bool vld[2];
      // issue phase: 8 gathers for two views
      #pragma unroll
      for (int t = 0; t < 2; t++) {
        int n = np*2 + t;
        float2 uv = uvbuf[((size_t)(b*N_ + n))*P_ + p];
        float sx = uv.x, sy = uv.y;
        float x0f = floorf(sx), y0f = floorf(sy);
        float fx = sx - x0f, fy = sy - y0f;
        int x0 = (int)x0f, y0 = (int)y0f;
        const unsigned short* base = val + ((size_t)(b*N_+n)*P_)*D_ + c*8;
        #pragma unroll
        for (int k = 0; k < 4; k++) {
          int dx = k & 1, dy = k >> 1;
          int cx = x0 + dx, cy = y0 + dy;
          bool inb = (cx >= 0) && (cx <= WF_-1) && (cy >= 0) && (cy <= HF_-1);
          int icx = min(max(cx,0),WF_-1), icy = min(max(cy,0),HF_-1);
          wm[t][k] = inb ? (dx ? fx : 1.f-fx) * (dy ? fy : 1.f-fy) : 0.f;
          g[t][k] = *(const uint4*)(base + (size_t)(icy*WF_ + icx)*D_);
        }
        vld[t] = (sx >= 0.f) && (sx <= (float)(WF_-1)) && (sy >= 0.f) && (sy <= (float)(HF_-1));
      }
      // math phase
      #pragma unroll
      for (int t = 0; t < 2; t++) {
        int n = np*2 + t;
        float acc[8];
        #pragma unroll
        for (int i = 0; i < 8; i++) acc[i] = 0.f;
        #pragma unroll
        for (int k = 0; k < 4; k++) {
          float gg[8];
          bfu2(g[t][k].x, gg[0], gg[1]); bfu2(g[t][k].y, gg[2], gg[3]);
          bfu2(g[t][k].z, gg[4], gg[5]); bfu2(g[t][k].w, gg[6], gg[7]);
          float w = wm[t][k];
          #pragma unroll
          for (int i = 0; i < 8; i++) acc[i] += gg[i]*w;
        }
        float ssp = 0.f, qsp = 0.f;
        #pragma unroll
        for (int i = 0; i < 8; i++) { ssp += acc[i]*acc[i]; qsp += qv[i]*acc[i]; }
        float ss = gred_sum(ssp);
        float qs = gred_sum(qsp);
        float dn = qs * qinv / fmaxf(sqrtf(ss), 1e-12f);
        dotv[n] = vld[t] ? dn : 0.f;
        #pragma unroll
        for (int i = 0; i < 8; i++) sv[n][i] = acc[i];
      }
    }
    // softmax over n
    float mx = dotv[0];
    #pragma unroll
    for (int n = 1; n < N_; n++) mx = fmaxf(mx, dotv[n]);
    float e[N_]; float den = 0.f;
    #pragma unroll
    for (int n = 0; n < N_; n++) { e[n] = expf(dotv[n]-mx); den += e[n]; }
    float rden = 1.f/den;
    float z[8];
    #pragma unroll
    for (int i = 0; i < 8; i++) z[i] = qv[i];
    #pragma unroll
    for (int n = 0; n < N_; n++) {
      float a = e[n]*rden;
      #pragma unroll
      for (int i = 0; i < 8; i++) z[i] += a*sv[n][i];
    }
    // LN1
    float sp = 0.f;
    #pragma unroll
    for (int i = 0; i < 8; i++) sp += z[i];
    float mu = gred_sum(sp) * (1.f/128.f);
    float vp = 0.f;
    #pragma unroll
    for (int i = 0; i < 8; i++) { float d0 = z[i]-mu; vp += d0*d0; }
    float rs = rsqrtf(gred_sum(vp) * (1.f/128.f) + 1e-5f);
    unsigned int ow[4];
    #pragma unroll
    for (int i = 0; i < 4; i++) {
      float o0 = (z[2*i]-mu)*rs*g1[2*i] + be1[2*i];
      float o1 = (z[2*i+1]-mu)*rs*g1[2*i+1] + be1[2*i+1];
      ow[i] = (unsigned int)f2bf(o0) | ((unsigned int)f2bf(o1) << 16);
    }
    *(uint4*)(zbuf + ((size_t)b*P_ + p)*D_ + c*8) = make_uint4(ow[0], ow[1], ow[2], ow[3]);
  }
}

// ---------------------------------------------------------------------------
// mlp (MFMA bf16): 32-p blocks (960 total), GEMM cols split across wave pairs,
// LN2 via cross-wave LDS partials. Output transposed via LDS.
// ---------------------------------------------------------------------------
__global__ __launch_bounds__(256) void mlp_kernel(const unsigned short* __restrict__ zbuf,
    const unsigned short* __restrict__ w1s, const float* __restrict__ b1,
    const unsigned short* __restrict__ w2s, const float* __restrict__ b2,
    const float* __restrict__ ln2_g, const float* __restrict__ ln2_b,
    float* __restrict__ out) {
  __shared__ __align__(16) char smem[26112];
  unsigned short* zt = (unsigned short*)smem;            // 32*136*2 = 8704 B
  unsigned short* ht = (unsigned short*)(smem + 8704);   // 32*264*2 = 16896 B
  float* lnp = (float*)(smem + 25600);                   // [2][32][2] fp32 = 512 B
  float* yt = (float*)smem;                              // 128*34*4 = 17408 B (alias)

  int tid = threadIdx.x;
  int b = blockIdx.y;
  int p0 = blockIdx.x * 32;
  int ln = tid & 63, wv = tid >> 6;
  int m = ln & 15, q = ln >> 4;
  int h = wv >> 1, ch2 = wv & 1;   // p-half, col-half

  #pragma unroll
  for (int i = 0; i < 2; i++) {
    int idx = tid + i*256;          // 512 = 32 p x 16 chunks of 8 d
    int pp = idx >> 4, ch = idx & 15;
    *(uint4*)&zt[pp*136 + ch*8] = *(const uint4*)(zbuf + ((size_t)b*P_ + p0 + pp)*D_ + ch*8);
  }
  __syncthreads();

  // GEMM1: 16 p x 128 cols per wave (8 col tiles), K=128
  floatx4 a1[8];
  #pragma unroll
  for (int j = 0; j < 8; j++) a1[j] = (floatx4){0.f,0.f,0.f,0.f};
  #pragma unroll
  for (int kc = 0; kc < 4; kc++) {
    short8 af = *(const short8*)&zt[(h*16+m)*136 + kc*32 + q*8];
    #pragma unroll
    for (int j = 0; j < 8; j++) {
      int dt = ch2*8 + j;
      short8 bfg = *(const short8*)(w1s + (((size_t)kc*16 + dt)*64 + ln)*8);
      a1[j] = __builtin_amdgcn_mfma_f32_16x16x32_bf16(af, bfg, a1[j], 0, 0, 0);
    }
  }
  #pragma unroll
  for (int j = 0; j < 8; j++) {
    int dt = ch2*8 + j;
    float bb = b1[dt*16 + m];
    #pragma unroll
    for (int r = 0; r < 4; r++) {
      float x = a1[j][r] + bb;
      float hv = 0.5f*x*(1.f + erff(x*0.70710678118654752f));
      ht[(h*16 + q*4 + r)*264 + dt*16 + m] = f2bf(hv);
    }
  }
  __syncthreads();

  // GEMM2: 16 p x 64 cols per wave (4 col tiles), K=256
  floatx4 a2[4];
  #pragma unroll
  for (int j = 0; j < 4; j++) a2[j] = (floatx4){0.f,0.f,0.f,0.f};
  #pragma unroll
  for (int kc = 0; kc < 8; kc++) {
    short8 af = *(const short8*)&ht[(h*16+m)*264 + kc*32 + q*8];
    #pragma unroll
    for (int j = 0; j < 4; j++) {
      int dt = ch2*4 + j;
      short8 bfg = *(const short8*)(w2s + (((size_t)kc*8 + dt)*64 + ln)*8);
      a2[j] = __builtin_amdgcn_mfma_f32_16x16x32_bf16(af, bfg, a2[j], 0, 0, 0);
    }
  }
  // bias + residual
  float y[4][4];
  #pragma unroll
  for (int j = 0; j < 4; j++) {
    int dt = ch2*4 + j;
    float bb = b2[dt*16 + m];
    #pragma unroll
    for (int r = 0; r < 4; r++) {
      int pp = h*16 + q*4 + r;
      y[j][r] = a2[j][r] + bb + bf2f(zt[pp*136 + dt*16 + m]);
    }
  }
  // LN2 partials (each wave covers 64 of 128 cols)
  #pragma unroll
  for (int r = 0; r < 4; r++) {
    float sp = 0.f, sq = 0.f;
    #pragma unroll
    for (int j = 0; j < 4; j++) { sp += y[j][r]; sq += y[j][r]*y[j][r]; }
    sp = gred_sum(sp); sq = gred_sum(sq);
    if (m == 0) {
      int pl = h*16 + q*4 + r;
      lnp[(ch2*32 + pl)*2 + 0] = sp;
      lnp[(ch2*32 + pl)*2 + 1] = sq;
    }
  }
  __syncthreads();
  float mu_[4], rs_[4];
  #pragma unroll
  for (int r = 0; r < 4; r++) {
    int pl = h*16 + q*4 + r;
    float sum = lnp[pl*2]     + lnp[(32+pl)*2];
    float ssq = lnp[pl*2 + 1] + lnp[(32+pl)*2 + 1];
    float mu = sum * (1.f/128.f);
    float var = fmaxf(ssq * (1.f/128.f) - mu*mu, 0.f);
    mu_[r] = mu; rs_[r] = rsqrtf(var + 1e-5f);
  }
  float gg[4], be[4];
  #pragma unroll
  for (int j = 0; j < 4; j++) {
    int d = (ch2*4 + j)*16 + m;
    gg[j] = ln2_g[d]; be[j] = ln2_b[d];
  }
  #pragma unroll
  for (int j = 0; j < 4; j++)
    #pragma unroll
    for (int r = 0; r < 4; r++)
      y[j][r] = (y[j][r] - mu_[r])*rs_[r]*gg[j] + be[j];
  __syncthreads();   // zt/ht/lnp reads done before yt alias writes
  #pragma unroll
  for (int j = 0; j < 4; j++)
    #pragma unroll
    for (int r = 0; r < 4; r++)
      yt[((ch2*4 + j)*16 + m)*34 + h*16 + q*4 + r] = y[j][r];
  __syncthreads();

  // transposed write: out[b, d, p0..p0+31]
  #pragma unroll
  for (int i = 0; i < 8; i++) {
    int idx = tid + i*256;    // 2048 float2 units = 128 d x 16
    int d = idx >> 4, pu = idx & 15;
    *(float2*)(out + ((size_t)(b*D_ + d))*P_ + p0 + pu*2) = *(float2*)&yt[d*34 + pu*2];
  }
}

// ---------------------------------------------------------------------------
extern "C" void kernel_launch(void* const* d_in, const int* in_sizes, int n_in,
                              void* d_out, int out_size, void* d_ws, size_t ws_size,
                              hipStream_t stream) {
  (void)in_sizes; (void)n_in; (void)out_size; (void)ws_size;
  const float* feature   = (const float*)d_in[0];
  const float* I_src     = (const float*)d_in[1];
  const float* I_tar_inv = (const float*)d_in[2];
  const float* E         = (const float*)d_in[3];
  const float* dis       = (const float*)d_in[4];
  const float* norm_vec  = (const float*)d_in[5];
  const float* bn_gamma  = (const float*)d_in[6];
  const float* bn_beta   = (const float*)d_in[7];
  const float* bn_mean   = (const float*)d_in[8];
  const float* bn_var    = (const float*)d_in[9];
  const float* conv_w    = (const float*)d_in[10];
  const float* ln1_g     = (const float*)d_in[11];
  const float* ln1_b     = (const float*)d_in[12];
  const float* mlp_w1    = (const float*)d_in[13];
  const float* mlp_b1    = (const float*)d_in[14];
  const float* mlp_w2    = (const float*)d_in[15];
  const float* mlp_b2    = (const float*)d_in[16];
  const float* ln2_g     = (const float*)d_in[17];
  const float* ln2_b     = (const float*)d_in[18];
  float* out = (float*)d_out;

  char* ws = (char*)d_ws;
  float* bnscale       = (float*)(ws + 0);
  float* bnbias        = (float*)(ws + 1024);
  float* Hm            = (float*)(ws + 2048);
  unsigned short* wswz = (unsigned short*)(ws + 4096);       // 64 KB
  unsigned short* w1s  = (unsigned short*)(ws + 69632);      // 64 KB
  unsigned short* w2s  = (unsigned short*)(ws + 135168);     // 64 KB
  float2* uvbuf        = (float2*)(ws + 200704);             // 1.47 MB
  unsigned short* val  = (unsigned short*)(ws + 1675264);              // bf16 (B,N,P,D) 47.2 MB
  unsigned short* zbuf = (unsigned short*)(ws + 1675264 + 47185920ULL);// bf16 (B,P,D) 7.9 MB

  hipLaunchKernelGGL(prep_kernel, dim3(1), dim3(256), 0, stream,
                     I_src, I_tar_inv, E, dis, norm_vec,
                     bn_gamma, bn_beta, bn_mean, bn_var, bnscale, bnbias, Hm);
  hipLaunchKernelGGL(uv_kernel, dim3(720), dim3(256), 0, stream, Hm, uvbuf);
  hipLaunchKernelGGL(swizzle_w_kernel, dim3(128), dim3(256), 0, stream, conv_w, wswz);
  hipLaunchKernelGGL(swizzle_mlp_kernel, dim3(256), dim3(256), 0, stream,
                     mlp_w1, mlp_w2, w1s, w2s);
  hipLaunchKernelGGL(conv_kernel, dim3(120, 24), dim3(256), 0, stream,
                     feature, wswz, bnscale, bnbias, val);
  hipLaunchKernelGGL(att_kernel, dim3(240, 4), dim3(256), 0, stream,
                     val, uvbuf, ln1_g, ln1_b, zbuf);
  hipLaunchKernelGGL(mlp_kernel, dim3(240, 4), dim3(256), 0, stream,
                     zbuf, w1s, mlp_b1, w2s, mlp_b2, ln2_g, ln2_b, out);
}